// Round 1
// baseline (802.399 us; speedup 1.0000x reference)
//
#include <hip/hip_runtime.h>

// HypergraphConv: out = LN( (H diag(1/d_e) H^T x) / d_v @ W_node + x @ W_res )
// Reassociated so the N x M x * GEMMs run at K-width 256, not 512.
//
// Pipeline (all on `stream`):
//  prep:   WT_cat[j][k] = concat(W_node, W_res)^T as bf16; zero d_e accumulator
//  gemmA:  partial[s] = (x^T H) split-K tiles; fused d_e column sums (atomics, exact ints)
//  reduce: T2T[j][m] = bf16( sum_s partial / max(d_e,1) )
//  gemmB:  T3[n][j] = bf16( (H @ T2) / d_v ), d_v fused per-block (exact ints)
//  gemmC:  out[n][:] = [T3 | x] @ WT_cat   (f32)
//  ln:     in-place LayerNorm over last dim with gamma/beta
//
// Workspace layout (bytes):
//   WT_cat  bf16 512*512          @ 0         (524288)
//   T2T     bf16 256*5120         @ 524288    (2621440)
//   T3      bf16 20000*256        @ 3145728   (10240000)
//   d_e     f32  5120             @ 13385728  (20480)
//   partial f32  8*256*5120       @ 13406208  (41943040)  -> total 55349248 B

#define N_NODES 20000
#define M_EDGES 5000
#define MPAD    5120
#define DIN     256
#define DOUT    512
#define SPLITS  8
#define KCHUNK  2560

typedef short bf16x8 __attribute__((ext_vector_type(8)));
typedef float f32x4 __attribute__((ext_vector_type(4)));

__device__ __forceinline__ unsigned short f2b(float f) {
  unsigned u = __builtin_bit_cast(unsigned, f);
  return (unsigned short)((u + 0x7FFFu + ((u >> 16) & 1u)) >> 16);  // RNE
}

// ---------------------------------------------------------------- prep
__global__ __launch_bounds__(256) void prep_kernel(const float* __restrict__ Wn,
                                                   const float* __restrict__ Wr,
                                                   unsigned short* __restrict__ WT,
                                                   float* __restrict__ de_acc) {
  const int q = blockIdx.x * 256 + threadIdx.x;
  if (q < 512 * 512) {
    const int j = q >> 9, k = q & 511;
    const float v = (k < 256) ? Wn[(size_t)k * 512 + j] : Wr[(size_t)(k - 256) * 512 + j];
    WT[(size_t)j * 512 + k] = f2b(v);
  }
  const int r = q - 512 * 512;
  if (r >= 0 && r < MPAD) de_acc[r] = 0.f;
}

// ---------------------------------------------------------------- GEMM-A: partial = x^T @ H  (M=256 j, N=5120 m, K=20000 n)
// grid (40 m-chunks, 2 j-chunks, 8 k-splits), 512 thr. Both operands transpose-staged.
__global__ __launch_bounds__(512) void gemmA_kernel(const float* __restrict__ x,
                                                    const float* __restrict__ H,
                                                    float* __restrict__ partial,
                                                    float* __restrict__ de_acc) {
  __shared__ unsigned short As[128 * 64];  // [j][k] bf16, 128B rows, XOR-swizzled
  __shared__ unsigned short Bs[128 * 64];  // [m][k]
  __shared__ float desh[128];
  const int t = threadIdx.x;
  const int m0 = blockIdx.x * 128;
  const int j0 = blockIdx.y * 128;
  const int s = blockIdx.z;

  if (t < 128) desh[t] = 0.f;
  float desum = 0.f;

  const int w = t >> 6, l = t & 63;
  const int wr = w >> 2, wc = w & 3;       // waves 2(row) x 4(col)
  const int lr = l & 15, lg = l >> 4;
  f32x4 acc[4][2];
#pragma unroll
  for (int i = 0; i < 4; ++i)
#pragma unroll
    for (int jq = 0; jq < 2; ++jq) acc[i][jq] = (f32x4){0.f, 0.f, 0.f, 0.f};

  const int sj = t & 127;   // staged column (j for A, m for B)
  const int sk0 = t >> 7;   // 0..3

  for (int st = 0; st < KCHUNK / 64; ++st) {
    const int k0 = s * KCHUNK + st * 64;
    __syncthreads();
    // stage A: As[j][k] = x[k0+k][j0+j], bf16 pair-packed b32 writes
#pragma unroll
    for (int p = 0; p < 8; ++p) {
      const int kp = sk0 + 4 * p;          // k-pair 0..31
      const int n = k0 + 2 * kp;
      const float v0 = (n < N_NODES) ? x[(size_t)n * DIN + j0 + sj] : 0.f;
      const float v1 = (n + 1 < N_NODES) ? x[(size_t)(n + 1) * DIN + j0 + sj] : 0.f;
      const unsigned pk = (unsigned)f2b(v0) | ((unsigned)f2b(v1) << 16);
      *(unsigned*)((char*)As + sj * 128 + ((kp * 4) ^ ((sj & 7) << 4))) = pk;
    }
    // stage B: Bs[m][k] = H[k0+k][m0+m]; fuse d_e partial sums
    const int gm = m0 + sj;
    const bool mv = gm < M_EDGES;
#pragma unroll
    for (int p = 0; p < 8; ++p) {
      const int kp = sk0 + 4 * p;
      const int n = k0 + 2 * kp;
      const float v0 = (mv && n < N_NODES) ? H[(size_t)n * M_EDGES + gm] : 0.f;
      const float v1 = (mv && n + 1 < N_NODES) ? H[(size_t)(n + 1) * M_EDGES + gm] : 0.f;
      desum += v0 + v1;
      const unsigned pk = (unsigned)f2b(v0) | ((unsigned)f2b(v1) << 16);
      *(unsigned*)((char*)Bs + sj * 128 + ((kp * 4) ^ ((sj & 7) << 4))) = pk;
    }
    __syncthreads();
#pragma unroll
    for (int ks = 0; ks < 2; ++ks) {
      const int kb = ks * 64 + 16 * lg;
      bf16x8 bf[2];
#pragma unroll
      for (int fc = 0; fc < 2; ++fc) {
        const int row = wc * 32 + fc * 16 + lr;
        bf[fc] = *(const bf16x8*)((const char*)Bs + row * 128 + (kb ^ ((row & 7) << 4)));
      }
#pragma unroll
      for (int fr = 0; fr < 4; ++fr) {
        const int row = wr * 64 + fr * 16 + lr;
        const bf16x8 af = *(const bf16x8*)((const char*)As + row * 128 + (kb ^ ((row & 7) << 4)));
#pragma unroll
        for (int fc = 0; fc < 2; ++fc)
          acc[fr][fc] = __builtin_amdgcn_mfma_f32_16x16x32_bf16(af, bf[fc], acc[fr][fc], 0, 0, 0);
      }
    }
  }
  // d_e: contribute once per (m-chunk, split): only j-block 0
  if (blockIdx.y == 0) {
    __syncthreads();
    atomicAdd(&desh[sj], desum);
    __syncthreads();
    if (t < 128) atomicAdd(&de_acc[m0 + t], desh[t]);
  }
  float* pp = partial + (size_t)s * (DIN * MPAD);
#pragma unroll
  for (int fr = 0; fr < 4; ++fr)
#pragma unroll
    for (int fc = 0; fc < 2; ++fc) {
      const int col = m0 + wc * 32 + fc * 16 + lr;
#pragma unroll
      for (int r = 0; r < 4; ++r) {
        const int row = j0 + wr * 64 + fr * 16 + 4 * lg + r;
        pp[(size_t)row * MPAD + col] = acc[fr][fc][r];
      }
    }
}

// ---------------------------------------------------------------- reduce: T2T = bf16(sum_s partial / max(d_e,1))
__global__ __launch_bounds__(256) void reduce_kernel(const float* __restrict__ partial,
                                                     const float* __restrict__ de_acc,
                                                     unsigned short* __restrict__ T2T) {
  const int idx = blockIdx.x * 256 + threadIdx.x;  // j*MPAD + m, < 256*MPAD
  const int m = idx % MPAD;
  float s = 0.f;
#pragma unroll
  for (int sp = 0; sp < SPLITS; ++sp) s += partial[(size_t)sp * (DIN * MPAD) + idx];
  T2T[idx] = f2b(s / fmaxf(de_acc[m], 1.f));
}

// ---------------------------------------------------------------- GEMM-B: T3 = bf16((H @ T2)/d_v)  (M=20000 n, N=256 j, K=5120 m)
// grid (313), 512 thr, BM=64 BN=256. d_v fused from A staging (full K per block).
__global__ __launch_bounds__(512) void gemmB_kernel(const float* __restrict__ H,
                                                    const unsigned short* __restrict__ T2T,
                                                    unsigned short* __restrict__ T3) {
  __shared__ unsigned short As[64 * 64];    // [node][m] bf16 swz
  __shared__ unsigned short Bs[256 * 64];   // [j][m] bf16 swz
  __shared__ float dvsh[64];
  const int t = threadIdx.x;
  const int n0 = blockIdx.x * 64;
  const int w = t >> 6, l = t & 63;        // waves 1 x 8 (j)
  const int lr = l & 15, lg = l >> 4;
  f32x4 acc[4][2];
#pragma unroll
  for (int i = 0; i < 4; ++i)
#pragma unroll
    for (int jq = 0; jq < 2; ++jq) acc[i][jq] = (f32x4){0.f, 0.f, 0.f, 0.f};
  float dv = 0.f;
  const int anode = t >> 3, ak8 = t & 7;

  for (int st = 0; st < MPAD / 64; ++st) {
    const int m0 = st * 64;
    __syncthreads();
    {  // stage A: H[n0+anode][m0+8*ak8 ..+7] -> bf16, fused d_v
      const int gn = n0 + anode;
      const int gm = m0 + ak8 * 8;
      float v[8];
      if (gn < N_NODES && gm + 7 < M_EDGES) {
        const float4* p4 = (const float4*)(H + (size_t)gn * M_EDGES + gm);
        const float4 q0 = p4[0], q1 = p4[1];
        v[0]=q0.x; v[1]=q0.y; v[2]=q0.z; v[3]=q0.w; v[4]=q1.x; v[5]=q1.y; v[6]=q1.z; v[7]=q1.w;
      } else {
#pragma unroll
        for (int j = 0; j < 8; ++j)
          v[j] = (gn < N_NODES && gm + j < M_EDGES) ? H[(size_t)gn * M_EDGES + gm + j] : 0.f;
      }
      bf16x8 pk;
      float sum = 0.f;
#pragma unroll
      for (int j = 0; j < 8; ++j) { sum += v[j]; pk[j] = (short)f2b(v[j]); }
      dv += sum;
      *(bf16x8*)((char*)As + anode * 128 + ((ak8 * 16) ^ ((anode & 7) << 4))) = pk;
    }
#pragma unroll
    for (int p = 0; p < 4; ++p) {  // stage B: T2T rows (bf16 passthrough)
      const int j = anode + p * 64;
      const bf16x8 pk = *(const bf16x8*)(T2T + (size_t)j * MPAD + m0 + ak8 * 8);
      *(bf16x8*)((char*)Bs + j * 128 + ((ak8 * 16) ^ ((j & 7) << 4))) = pk;
    }
    __syncthreads();
#pragma unroll
    for (int ks = 0; ks < 2; ++ks) {
      const int kb = ks * 64 + 16 * lg;
      bf16x8 bf[2];
#pragma unroll
      for (int fc = 0; fc < 2; ++fc) {
        const int row = w * 32 + fc * 16 + lr;
        bf[fc] = *(const bf16x8*)((const char*)Bs + row * 128 + (kb ^ ((row & 7) << 4)));
      }
#pragma unroll
      for (int fr = 0; fr < 4; ++fr) {
        const int row = fr * 16 + lr;
        const bf16x8 af = *(const bf16x8*)((const char*)As + row * 128 + (kb ^ ((row & 7) << 4)));
#pragma unroll
        for (int fc = 0; fc < 2; ++fc)
          acc[fr][fc] = __builtin_amdgcn_mfma_f32_16x16x32_bf16(af, bf[fc], acc[fr][fc], 0, 0, 0);
      }
    }
  }
  dv += __shfl_xor(dv, 1, 64);
  dv += __shfl_xor(dv, 2, 64);
  dv += __shfl_xor(dv, 4, 64);
  __syncthreads();
  if ((t & 7) == 0) dvsh[anode] = dv;
  __syncthreads();
#pragma unroll
  for (int fr = 0; fr < 4; ++fr)
#pragma unroll
    for (int r = 0; r < 4; ++r) {
      const int node = fr * 16 + 4 * lg + r;
      const int gn = n0 + node;
      if (gn < N_NODES) {
        const float inv = 1.f / fmaxf(dvsh[node], 1.f);
#pragma unroll
        for (int fc = 0; fc < 2; ++fc) {
          const int j = w * 32 + fc * 16 + lr;
          T3[(size_t)gn * DIN + j] = f2b(acc[fr][fc][r] * inv);
        }
      }
    }
}

// ---------------------------------------------------------------- GEMM-C: out = [T3 | x] @ WT_cat  (M=20000, N=512, K=512)
// grid (157, 4), 512 thr, BM=128 BN=128.
__global__ __launch_bounds__(512) void gemmC_kernel(const float* __restrict__ x,
                                                    const unsigned short* __restrict__ T3,
                                                    const unsigned short* __restrict__ WT,
                                                    float* __restrict__ out) {
  __shared__ unsigned short As[128 * 64];
  __shared__ unsigned short Bs[128 * 64];
  const int t = threadIdx.x;
  const int n0 = blockIdx.x * 128;
  const int j0 = blockIdx.y * 128;
  const int w = t >> 6, l = t & 63;
  const int wr = w >> 2, wc = w & 3;
  const int lr = l & 15, lg = l >> 4;
  f32x4 acc[4][2];
#pragma unroll
  for (int i = 0; i < 4; ++i)
#pragma unroll
    for (int jq = 0; jq < 2; ++jq) acc[i][jq] = (f32x4){0.f, 0.f, 0.f, 0.f};
  const int sr = t >> 3, sk8 = t & 7;

  for (int st = 0; st < 8; ++st) {
    __syncthreads();
#pragma unroll
    for (int p = 0; p < 2; ++p) {  // stage A: k<256 from T3 (bf16), k>=256 from x (f32)
      const int node = sr + p * 64;
      const int gn = n0 + node;
      bf16x8 pk;
      if (st < 4) {
        if (gn < N_NODES)
          pk = *(const bf16x8*)(T3 + (size_t)gn * DIN + st * 64 + sk8 * 8);
        else {
#pragma unroll
          for (int j = 0; j < 8; ++j) pk[j] = 0;
        }
      } else {
        if (gn < N_NODES) {
          const float4* p4 = (const float4*)(x + (size_t)gn * DIN + (st - 4) * 64 + sk8 * 8);
          const float4 q0 = p4[0], q1 = p4[1];
          pk[0]=(short)f2b(q0.x); pk[1]=(short)f2b(q0.y); pk[2]=(short)f2b(q0.z); pk[3]=(short)f2b(q0.w);
          pk[4]=(short)f2b(q1.x); pk[5]=(short)f2b(q1.y); pk[6]=(short)f2b(q1.z); pk[7]=(short)f2b(q1.w);
        } else {
#pragma unroll
          for (int j = 0; j < 8; ++j) pk[j] = 0;
        }
      }
      *(bf16x8*)((char*)As + node * 128 + ((sk8 * 16) ^ ((node & 7) << 4))) = pk;
    }
#pragma unroll
    for (int p = 0; p < 2; ++p) {  // stage B: WT_cat rows
      const int j = sr + p * 64;
      const bf16x8 pk = *(const bf16x8*)(WT + (size_t)(j0 + j) * 512 + st * 64 + sk8 * 8);
      *(bf16x8*)((char*)Bs + j * 128 + ((sk8 * 16) ^ ((j & 7) << 4))) = pk;
    }
    __syncthreads();
#pragma unroll
    for (int ks = 0; ks < 2; ++ks) {
      const int kb = ks * 64 + 16 * lg;
      bf16x8 bf[2];
#pragma unroll
      for (int fc = 0; fc < 2; ++fc) {
        const int row = wc * 32 + fc * 16 + lr;
        bf[fc] = *(const bf16x8*)((const char*)Bs + row * 128 + (kb ^ ((row & 7) << 4)));
      }
#pragma unroll
      for (int fr = 0; fr < 4; ++fr) {
        const int row = wr * 64 + fr * 16 + lr;
        const bf16x8 af = *(const bf16x8*)((const char*)As + row * 128 + (kb ^ ((row & 7) << 4)));
#pragma unroll
        for (int fc = 0; fc < 2; ++fc)
          acc[fr][fc] = __builtin_amdgcn_mfma_f32_16x16x32_bf16(af, bf[fc], acc[fr][fc], 0, 0, 0);
      }
    }
  }
#pragma unroll
  for (int fr = 0; fr < 4; ++fr)
#pragma unroll
    for (int fc = 0; fc < 2; ++fc) {
      const int col = j0 + wc * 32 + fc * 16 + lr;
#pragma unroll
      for (int r = 0; r < 4; ++r) {
        const int row = n0 + wr * 64 + fr * 16 + 4 * lg + r;
        if (row < N_NODES) out[(size_t)row * DOUT + col] = acc[fr][fc][r];
      }
    }
}

// ---------------------------------------------------------------- LayerNorm (in place on out)
__global__ __launch_bounds__(256) void ln_kernel(float* __restrict__ out,
                                                 const float* __restrict__ gamma,
                                                 const float* __restrict__ beta) {
  const int row = blockIdx.x * 4 + (threadIdx.x >> 6);
  const int l = threadIdx.x & 63;
  float* p = out + (size_t)row * DOUT;
  float4 va = *(const float4*)(p + 4 * l);
  float4 vb = *(const float4*)(p + 256 + 4 * l);
  float s = va.x + va.y + va.z + va.w + vb.x + vb.y + vb.z + vb.w;
  float s2 = va.x*va.x + va.y*va.y + va.z*va.z + va.w*va.w +
             vb.x*vb.x + vb.y*vb.y + vb.z*vb.z + vb.w*vb.w;
#pragma unroll
  for (int m = 1; m < 64; m <<= 1) { s += __shfl_xor(s, m, 64); s2 += __shfl_xor(s2, m, 64); }
  const float mu = s * (1.f / DOUT);
  const float rs = rsqrtf(s2 * (1.f / DOUT) - mu * mu + 1e-5f);
  const float4 g0 = *(const float4*)(gamma + 4 * l);
  const float4 g1 = *(const float4*)(gamma + 256 + 4 * l);
  const float4 b0 = *(const float4*)(beta + 4 * l);
  const float4 b1 = *(const float4*)(beta + 256 + 4 * l);
  va.x = (va.x - mu) * rs * g0.x + b0.x;  va.y = (va.y - mu) * rs * g0.y + b0.y;
  va.z = (va.z - mu) * rs * g0.z + b0.z;  va.w = (va.w - mu) * rs * g0.w + b0.w;
  vb.x = (vb.x - mu) * rs * g1.x + b1.x;  vb.y = (vb.y - mu) * rs * g1.y + b1.y;
  vb.z = (vb.z - mu) * rs * g1.z + b1.z;  vb.w = (vb.w - mu) * rs * g1.w + b1.w;
  *(float4*)(p + 4 * l) = va;
  *(float4*)(p + 256 + 4 * l) = vb;
}

// ----------------------------------------------------------------
extern "C" void kernel_launch(void* const* d_in, const int* in_sizes, int n_in,
                              void* d_out, int out_size, void* d_ws, size_t ws_size,
                              hipStream_t stream) {
  (void)in_sizes; (void)n_in; (void)out_size; (void)ws_size;
  const float* x = (const float*)d_in[0];
  const float* H = (const float*)d_in[1];
  const float* Wn = (const float*)d_in[2];
  const float* Wr = (const float*)d_in[3];
  const float* gamma = (const float*)d_in[4];
  const float* beta = (const float*)d_in[5];
  float* out = (float*)d_out;
  char* ws = (char*)d_ws;

  unsigned short* WT = (unsigned short*)(ws);
  unsigned short* T2T = (unsigned short*)(ws + 524288);
  unsigned short* T3 = (unsigned short*)(ws + 3145728);
  float* de_acc = (float*)(ws + 13385728);
  float* partial = (float*)(ws + 13406208);

  prep_kernel<<<dim3(1044), dim3(256), 0, stream>>>(Wn, Wr, WT, de_acc);
  gemmA_kernel<<<dim3(40, 2, 8), dim3(512), 0, stream>>>(x, H, partial, de_acc);
  reduce_kernel<<<dim3(5120), dim3(256), 0, stream>>>(partial, de_acc, T2T);
  gemmB_kernel<<<dim3(313), dim3(512), 0, stream>>>(H, T2T, T3);
  gemmC_kernel<<<dim3(157, 4), dim3(512), 0, stream>>>(x, T3, WT, out);
  ln_kernel<<<dim3(5000), dim3(256), 0, stream>>>(out, gamma, beta);
}

// Round 2
// 590.292 us; speedup vs baseline: 1.3593x; 1.3593x over previous
//
#include <hip/hip_runtime.h>

// HypergraphConv: out = LN( (H diag(1/d_e) H^T x) / d_v @ W_node + x @ W_res )
//
// Round-2 structure: H (exactly 0/1) is bit-packed once into BOTH orientations
// (12.8 MB each, L2/L3-resident); aggregation GEMMs expand bits -> bf16 MFMA
// fragments in registers (no LDS for that operand) and pull the dense operand
// from pre-swizzled global "LDS images" via global_load_lds (linear DMA writes,
// conflict-free swizzled reads). Degrees = exact popcounts.
//
// Pipeline: prep(WT) | xt(x->swizzled imgs) | pack(H->bits) -> deg ->
//   gemmA (xT @ H, split-K=4, bf16 partials) -> reduce (-> T2T imgs) ->
//   gemmB (H @ T2 -> T3 bf16) -> gemmC ([T3|x] @ WT) -> ln
//
// Workspace (bytes):
//   WT      bf16 512x512      @ 0          (524,288)
//   Hb      u64  80x20480     @ 524,288    (13,107,200)   [mw][n]
//   HTb     u64  320x5120     @ 13,631,488 (13,107,200)   [nw][m]
//   inv_de  f32  5120         @ 26,738,688 (20,480)
//   inv_dv  f32  20480        @ 26,759,168 (81,920)
//   xT_img  2x320x16KB        @ 26,841,088 (10,485,760)   [T2T_img 80x32KB aliased here after gemmA]
//   partial bf16 4x256x5120   @ 37,326,848 (10,485,760)   [T3 20032x256 bf16 aliased here after reduce]
//   total 47,812,608 < 55,349,248 (proven available in round 1)

#define N_NODES 20000
#define M_EDGES 5000
#define MPAD    5120
#define NPAD    20480
#define NW      320
#define MW      80
#define DIN     256
#define DOUT    512
#define SPLITS  4
#define KSTEPS_A 80

typedef short bf16x8 __attribute__((ext_vector_type(8)));
typedef float f32x4 __attribute__((ext_vector_type(4)));
typedef unsigned long long u64;

__device__ __forceinline__ unsigned short f2b(float f) {
  unsigned u = __builtin_bit_cast(unsigned, f);
  return (unsigned short)((u + 0x7FFFu + ((u >> 16) & 1u)) >> 16);  // RNE
}

__device__ __forceinline__ void stage16(const void* g, void* l) {
  __builtin_amdgcn_global_load_lds(
      (const __attribute__((address_space(1))) unsigned int*)g,
      (__attribute__((address_space(3))) unsigned int*)l, 16, 0, 0);
}

// 8 bits -> 8 bf16 (0.0/1.0) packed as bf16x8
__device__ __forceinline__ bf16x8 expand_bits8(unsigned w8) {
  union { unsigned u[4]; bf16x8 v; } r;
#pragma unroll
  for (int p = 0; p < 4; ++p) {
    const unsigned b = (w8 >> (2 * p)) & 3u;
    r.u[p] = (b & 1u) * 0x3F80u + (b & 2u) * 0x1FC00000u;  // lo=bit0, hi=bit1
  }
  return r.v;
}

// ---------------------------------------------------------------- prep: WT_cat = concat(Wn,Wr)^T bf16
__global__ __launch_bounds__(256) void prep_kernel(const float* __restrict__ Wn,
                                                   const float* __restrict__ Wr,
                                                   unsigned short* __restrict__ WT) {
  const int q = blockIdx.x * 256 + threadIdx.x;  // < 262144
  const int j = q >> 9, k = q & 511;
  const float v = (k < 256) ? Wn[(size_t)k * 512 + j] : Wr[(size_t)(k - 256) * 512 + j];
  WT[(size_t)j * 512 + k] = f2b(v);
}

// ---------------------------------------------------------------- xt: x -> swizzled bf16 LDS-image tiles
// img[(jb*320+kt)] 16KB: byte(r,k) = r*128 + ((k*2) ^ ((r&7)<<4)), r=j_local<128, k=n_local<64
__global__ __launch_bounds__(256) void xt_kernel(const float* __restrict__ x,
                                                 char* __restrict__ img) {
  __shared__ float fx[64 * 129];
  const int t = threadIdx.x;
  const int kt = blockIdx.x;   // 0..319
  const int jb = blockIdx.y;   // 0..1
  const int n0 = kt * 64;
#pragma unroll
  for (int p = 0; p < 8; ++p) {
    const int e = p * 1024 + t * 4;
    const int nl = e >> 7;       // 0..63
    const int j4 = e & 127;      // col, step 4
    float4 v = make_float4(0.f, 0.f, 0.f, 0.f);
    if (n0 + nl < N_NODES) v = *(const float4*)(x + (size_t)(n0 + nl) * DIN + jb * 128 + j4);
    fx[nl * 129 + j4 + 0] = v.x;
    fx[nl * 129 + j4 + 1] = v.y;
    fx[nl * 129 + j4 + 2] = v.z;
    fx[nl * 129 + j4 + 3] = v.w;
  }
  __syncthreads();
  char* ob = img + ((size_t)jb * NW + kt) * 16384;
#pragma unroll
  for (int q = 0; q < 16; ++q) {
    const int slot = q * 256 + t;   // < 4096
    const int r = slot >> 5;        // j_local
    const int pk = slot & 31;       // n-pair
    const float v0 = fx[(2 * pk) * 129 + r];
    const float v1 = fx[(2 * pk + 1) * 129 + r];
    const unsigned u = (unsigned)f2b(v0) | ((unsigned)f2b(v1) << 16);
    *(unsigned*)(ob + r * 128 + ((pk * 4) ^ ((r & 7) << 4))) = u;
  }
}

// ---------------------------------------------------------------- pack: H f32 -> bitmasks, both orientations
__global__ __launch_bounds__(256) void pack_kernel(const float* __restrict__ H,
                                                   u64* __restrict__ Hb,
                                                   u64* __restrict__ HTb) {
  const int t = threadIdx.x;
  const int w = t >> 6, l = t & 63;
  const int nb = blockIdx.x;   // 0..319
  const int mb = blockIdx.y;   // 0..19
  const int m = mb * 256 + w * 64 + l;
  const bool mv = m < M_EDGES;
  unsigned lo = 0, hi = 0;
  u64 myword = 0;
#pragma unroll 8
  for (int k = 0; k < 64; ++k) {
    const int n = nb * 64 + k;
    float v = 0.f;
    if (mv && n < N_NODES) v = H[(size_t)n * M_EDGES + m];
    const bool p = (v != 0.f);
    const u64 mask = __ballot(p);
    if (l == k) myword = mask;                  // stash row-n word in lane k
    if (k < 32) lo |= (p ? 1u : 0u) << k;
    else        hi |= (p ? 1u : 0u) << (k - 32);
  }
  Hb[(size_t)(mb * 4 + w) * NPAD + nb * 64 + l] = myword;       // [mw][n]
  HTb[(size_t)nb * MPAD + m] = ((u64)hi << 32) | lo;            // [nw][m]
}

// ---------------------------------------------------------------- deg: exact popcount degrees -> reciprocals
__global__ __launch_bounds__(256) void deg_kernel(const u64* __restrict__ Hb,
                                                  const u64* __restrict__ HTb,
                                                  float* __restrict__ inv_de,
                                                  float* __restrict__ inv_dv) {
  const int g = blockIdx.x * 256 + threadIdx.x;
  if (g < MPAD) {
    int c = 0;
    for (int nw = 0; nw < NW; ++nw) c += __popcll(HTb[(size_t)nw * MPAD + g]);
    inv_de[g] = 1.f / fmaxf((float)c, 1.f);
  } else if (g < MPAD + NPAD) {
    const int n = g - MPAD;
    int c = 0;
#pragma unroll
    for (int mw = 0; mw < MW; ++mw) c += __popcll(Hb[(size_t)mw * NPAD + n]);
    inv_dv[n] = 1.f / fmaxf((float)c, 1.f);
  }
}

// ---------------------------------------------------------------- gemmA: partial[s] = (x^T @ H) split-K
// C rows j<256 (A = xT images via lds-DMA), cols m<5120 (B = HT bits, reg-expanded)
__global__ __launch_bounds__(512) void gemmA_kernel(const char* __restrict__ xT_img,
                                                    const u64* __restrict__ HTb,
                                                    unsigned short* __restrict__ partial) {
  __shared__ char As[2][16384];
  const int t = threadIdx.x;
  const int m0 = blockIdx.x * 128;
  const int jb = blockIdx.y;
  const int s  = blockIdx.z;
  const int w = t >> 6, l = t & 63;
  const int wr = w >> 2, wc = w & 3;
  const int lr = l & 15, lg = l >> 4;
  const int shl8 = lg * 8;

  f32x4 acc[4][2];
#pragma unroll
  for (int i = 0; i < 4; ++i)
#pragma unroll
    for (int jq = 0; jq < 2; ++jq) acc[i][jq] = (f32x4){0.f, 0.f, 0.f, 0.f};

  const char* img = xT_img + ((size_t)jb * NW + s * KSTEPS_A) * 16384;
  {  // prologue stage tile 0
    const char* src = img + w * 2048 + l * 16;
    stage16(src,        &As[0][w * 2048]);
    stage16(src + 1024, &As[0][w * 2048 + 1024]);
  }
  const u64* hrow = HTb + (size_t)(s * KSTEPS_A) * MPAD + m0 + wc * 32 + lr;
  const int abase = (wr * 64 + lr) * 128;
  const int aswz = (lr & 7) << 4;

  for (int st = 0; st < KSTEPS_A; ++st) {
    const u64 b0 = hrow[(size_t)st * MPAD];        // fc=0 word
    const u64 b1 = hrow[(size_t)st * MPAD + 16];   // fc=1 word
    const int cur = st & 1;
    if (st + 1 < KSTEPS_A) {
      const char* src = img + (size_t)(st + 1) * 16384 + w * 2048 + l * 16;
      stage16(src,        &As[cur ^ 1][w * 2048]);
      stage16(src + 1024, &As[cur ^ 1][w * 2048 + 1024]);
      asm volatile("s_waitcnt vmcnt(4)" ::: "memory");  // cur tile done; b + next tile in flight
    } else {
      asm volatile("s_waitcnt vmcnt(2)" ::: "memory");  // cur tile done; b in flight
    }
    __builtin_amdgcn_s_barrier();
    const char* Ab = As[cur];
#pragma unroll
    for (int ks = 0; ks < 2; ++ks) {
      bf16x8 bfr0, bfr1;
      {
        const unsigned h0 = (unsigned)(b0 >> (ks * 32));
        const unsigned h1 = (unsigned)(b1 >> (ks * 32));
        bfr0 = expand_bits8((h0 >> shl8) & 255u);
        bfr1 = expand_bits8((h1 >> shl8) & 255u);
      }
      const int koff = (ks * 64 + lg * 16) ^ aswz;
#pragma unroll
      for (int fr = 0; fr < 4; ++fr) {
        const bf16x8 af = *(const bf16x8*)(Ab + abase + fr * 2048 + koff);
        acc[fr][0] = __builtin_amdgcn_mfma_f32_16x16x32_bf16(af, bfr0, acc[fr][0], 0, 0, 0);
        acc[fr][1] = __builtin_amdgcn_mfma_f32_16x16x32_bf16(af, bfr1, acc[fr][1], 0, 0, 0);
      }
    }
    __builtin_amdgcn_s_barrier();
  }
  unsigned short* pp = partial + (size_t)s * (DIN * MPAD);
#pragma unroll
  for (int fr = 0; fr < 4; ++fr) {
    const int row = jb * 128 + wr * 64 + fr * 16 + 4 * lg;
#pragma unroll
    for (int fc = 0; fc < 2; ++fc) {
      const int col = m0 + wc * 32 + fc * 16 + lr;
#pragma unroll
      for (int r = 0; r < 4; ++r)
        pp[(size_t)(row + r) * MPAD + col] = f2b(acc[fr][fc][r]);
    }
  }
}

// ---------------------------------------------------------------- reduce: sum partials, /d_e, emit T2T images
// T2T img[mt] 32KB: byte(j,mloc) = j*128 + ((mloc*2) ^ ((j&7)<<4))
__global__ __launch_bounds__(256) void reduce_kernel(const unsigned short* __restrict__ partial,
                                                     const float* __restrict__ inv_de,
                                                     char* __restrict__ t2img) {
  const int g = blockIdx.x * 256 + threadIdx.x;  // < 163840
  const int j = g / 640;
  const int m8 = g - j * 640;
  float sum[8] = {0.f, 0.f, 0.f, 0.f, 0.f, 0.f, 0.f, 0.f};
#pragma unroll
  for (int s = 0; s < SPLITS; ++s) {
    const bf16x8 v = *(const bf16x8*)(partial + (size_t)s * (DIN * MPAD) + (size_t)j * MPAD + m8 * 8);
#pragma unroll
    for (int i = 0; i < 8; ++i)
      sum[i] += __builtin_bit_cast(float, ((unsigned)(unsigned short)v[i]) << 16);
  }
  const float4 e0 = *(const float4*)(inv_de + m8 * 8);
  const float4 e1 = *(const float4*)(inv_de + m8 * 8 + 4);
  const float e[8] = {e0.x, e0.y, e0.z, e0.w, e1.x, e1.y, e1.z, e1.w};
  unsigned uo[4];
#pragma unroll
  for (int p = 0; p < 4; ++p) {
    const unsigned lo = f2b(sum[2 * p] * e[2 * p]);
    const unsigned hi = f2b(sum[2 * p + 1] * e[2 * p + 1]);
    uo[p] = lo | (hi << 16);
  }
  const uint4 o = make_uint4(uo[0], uo[1], uo[2], uo[3]);
  const int mt = m8 >> 3;
  *(uint4*)(t2img + (size_t)mt * 32768 + j * 128 + (((m8 & 7) * 16) ^ ((j & 7) << 4))) = o;
}

// ---------------------------------------------------------------- gemmB: T3 = bf16((H @ T2)/d_v)
// C rows n (A = H bits, reg-expanded), cols j<256 (B = T2T images via lds-DMA)
__global__ __launch_bounds__(512) void gemmB_kernel(const char* __restrict__ t2img,
                                                    const u64* __restrict__ Hb,
                                                    const float* __restrict__ inv_dv,
                                                    unsigned short* __restrict__ T3) {
  __shared__ char Bs[2][32768];
  __shared__ float dvsh[64];
  const int t = threadIdx.x;
  const int n0 = blockIdx.x * 64;
  const int w = t >> 6, l = t & 63;
  const int lr = l & 15, lg = l >> 4;
  const int shl8 = lg * 8;
  if (t < 64) dvsh[t] = inv_dv[n0 + t];
  __syncthreads();

  f32x4 acc[4][2];
#pragma unroll
  for (int i = 0; i < 4; ++i)
#pragma unroll
    for (int jq = 0; jq < 2; ++jq) acc[i][jq] = (f32x4){0.f, 0.f, 0.f, 0.f};

  {  // prologue stage tile 0
    const char* src = t2img + w * 4096 + l * 16;
    stage16(src,        &Bs[0][w * 4096]);
    stage16(src + 1024, &Bs[0][w * 4096 + 1024]);
    stage16(src + 2048, &Bs[0][w * 4096 + 2048]);
    stage16(src + 3072, &Bs[0][w * 4096 + 3072]);
  }
  const u64* arow = Hb + n0 + lr;
  const int bbase = (w * 32 + lr) * 128;
  const int bswz = (lr & 7) << 4;

  for (int st = 0; st < MW; ++st) {
    const u64 a0 = arow[(size_t)st * NPAD];
    const u64 a1 = arow[(size_t)st * NPAD + 16];
    const u64 a2 = arow[(size_t)st * NPAD + 32];
    const u64 a3 = arow[(size_t)st * NPAD + 48];
    const int cur = st & 1;
    if (st + 1 < MW) {
      const char* src = t2img + (size_t)(st + 1) * 32768 + w * 4096 + l * 16;
      stage16(src,        &Bs[cur ^ 1][w * 4096]);
      stage16(src + 1024, &Bs[cur ^ 1][w * 4096 + 1024]);
      stage16(src + 2048, &Bs[cur ^ 1][w * 4096 + 2048]);
      stage16(src + 3072, &Bs[cur ^ 1][w * 4096 + 3072]);
      asm volatile("s_waitcnt vmcnt(8)" ::: "memory");  // cur tile done; bits + next tile in flight
    } else {
      asm volatile("s_waitcnt vmcnt(4)" ::: "memory");
    }
    __builtin_amdgcn_s_barrier();
    const char* Bb = Bs[cur];
#pragma unroll
    for (int ks = 0; ks < 2; ++ks) {
      const int koff = (ks * 64 + lg * 16) ^ bswz;
      const bf16x8 bf0 = *(const bf16x8*)(Bb + bbase + koff);
      const bf16x8 bf1 = *(const bf16x8*)(Bb + bbase + 2048 + koff);
#pragma unroll
      for (int fr = 0; fr < 4; ++fr) {
        const u64 av = (fr == 0) ? a0 : (fr == 1) ? a1 : (fr == 2) ? a2 : a3;
        const unsigned h = (unsigned)(av >> (ks * 32));
        const bf16x8 af = expand_bits8((h >> shl8) & 255u);
        acc[fr][0] = __builtin_amdgcn_mfma_f32_16x16x32_bf16(af, bf0, acc[fr][0], 0, 0, 0);
        acc[fr][1] = __builtin_amdgcn_mfma_f32_16x16x32_bf16(af, bf1, acc[fr][1], 0, 0, 0);
      }
    }
    __builtin_amdgcn_s_barrier();
  }
#pragma unroll
  for (int fr = 0; fr < 4; ++fr) {
#pragma unroll
    for (int r = 0; r < 4; ++r) {
      const int nl = fr * 16 + 4 * lg + r;
      const int gn = n0 + nl;
      if (gn < N_NODES) {
        const float inv = dvsh[nl];
#pragma unroll
        for (int fc = 0; fc < 2; ++fc) {
          const int j = w * 32 + fc * 16 + lr;
          T3[(size_t)gn * DIN + j] = f2b(acc[fr][fc][r] * inv);
        }
      }
    }
  }
}

// ---------------------------------------------------------------- gemmC: out = [T3 | x] @ WT_cat (f32)
__global__ __launch_bounds__(512) void gemmC_kernel(const float* __restrict__ x,
                                                    const unsigned short* __restrict__ T3,
                                                    const unsigned short* __restrict__ WT,
                                                    float* __restrict__ out) {
  __shared__ unsigned short As[128 * 64];
  __shared__ unsigned short Bsh[128 * 64];
  const int t = threadIdx.x;
  const int n0 = blockIdx.x * 128;
  const int j0 = blockIdx.y * 128;
  const int w = t >> 6, l = t & 63;
  const int wr = w >> 2, wc = w & 3;
  const int lr = l & 15, lg = l >> 4;
  f32x4 acc[4][2];
#pragma unroll
  for (int i = 0; i < 4; ++i)
#pragma unroll
    for (int jq = 0; jq < 2; ++jq) acc[i][jq] = (f32x4){0.f, 0.f, 0.f, 0.f};
  const int sr = t >> 3, sk8 = t & 7;

  for (int st = 0; st < 8; ++st) {
    __syncthreads();
#pragma unroll
    for (int p = 0; p < 2; ++p) {  // stage A: k<256 from T3 (bf16), k>=256 from x (f32)
      const int node = sr + p * 64;
      const int gn = n0 + node;
      bf16x8 pk;
      if (st < 4) {
        if (gn < N_NODES)
          pk = *(const bf16x8*)(T3 + (size_t)gn * DIN + st * 64 + sk8 * 8);
        else {
#pragma unroll
          for (int jq = 0; jq < 8; ++jq) pk[jq] = 0;
        }
      } else {
        if (gn < N_NODES) {
          const float4* p4 = (const float4*)(x + (size_t)gn * DIN + (st - 4) * 64 + sk8 * 8);
          const float4 q0 = p4[0], q1 = p4[1];
          pk[0] = (short)f2b(q0.x); pk[1] = (short)f2b(q0.y); pk[2] = (short)f2b(q0.z); pk[3] = (short)f2b(q0.w);
          pk[4] = (short)f2b(q1.x); pk[5] = (short)f2b(q1.y); pk[6] = (short)f2b(q1.z); pk[7] = (short)f2b(q1.w);
        } else {
#pragma unroll
          for (int jq = 0; jq < 8; ++jq) pk[jq] = 0;
        }
      }
      *(bf16x8*)((char*)As + node * 128 + ((sk8 * 16) ^ ((node & 7) << 4))) = pk;
    }
#pragma unroll
    for (int p = 0; p < 2; ++p) {  // stage B: WT rows
      const int j = sr + p * 64;
      const bf16x8 pk = *(const bf16x8*)(WT + (size_t)(j0 + j) * 512 + st * 64 + sk8 * 8);
      *(bf16x8*)((char*)Bsh + j * 128 + ((sk8 * 16) ^ ((j & 7) << 4))) = pk;
    }
    __syncthreads();
#pragma unroll
    for (int ks = 0; ks < 2; ++ks) {
      const int kb = ks * 64 + 16 * lg;
      bf16x8 bf[2];
#pragma unroll
      for (int fc = 0; fc < 2; ++fc) {
        const int row = wc * 32 + fc * 16 + lr;
        bf[fc] = *(const bf16x8*)((const char*)Bsh + row * 128 + (kb ^ ((row & 7) << 4)));
      }
#pragma unroll
      for (int fr = 0; fr < 4; ++fr) {
        const int row = wr * 64 + fr * 16 + lr;
        const bf16x8 af = *(const bf16x8*)((const char*)As + row * 128 + (kb ^ ((row & 7) << 4)));
#pragma unroll
        for (int fc = 0; fc < 2; ++fc)
          acc[fr][fc] = __builtin_amdgcn_mfma_f32_16x16x32_bf16(af, bf[fc], acc[fr][fc], 0, 0, 0);
      }
    }
  }
#pragma unroll
  for (int fr = 0; fr < 4; ++fr)
#pragma unroll
    for (int fc = 0; fc < 2; ++fc) {
      const int col = j0 + wc * 32 + fc * 16 + lr;
#pragma unroll
      for (int r = 0; r < 4; ++r) {
        const int row = n0 + wr * 64 + fr * 16 + 4 * lg + r;
        if (row < N_NODES) out[(size_t)row * DOUT + col] = acc[fr][fc][r];
      }
    }
}

// ---------------------------------------------------------------- LayerNorm (in place on out)
__global__ __launch_bounds__(256) void ln_kernel(float* __restrict__ out,
                                                 const float* __restrict__ gamma,
                                                 const float* __restrict__ beta) {
  const int row = blockIdx.x * 4 + (threadIdx.x >> 6);
  const int l = threadIdx.x & 63;
  float* p = out + (size_t)row * DOUT;
  float4 va = *(const float4*)(p + 4 * l);
  float4 vb = *(const float4*)(p + 256 + 4 * l);
  float s = va.x + va.y + va.z + va.w + vb.x + vb.y + vb.z + vb.w;
  float s2 = va.x * va.x + va.y * va.y + va.z * va.z + va.w * va.w +
             vb.x * vb.x + vb.y * vb.y + vb.z * vb.z + vb.w * vb.w;
#pragma unroll
  for (int m = 1; m < 64; m <<= 1) { s += __shfl_xor(s, m, 64); s2 += __shfl_xor(s2, m, 64); }
  const float mu = s * (1.f / DOUT);
  const float rs = rsqrtf(s2 * (1.f / DOUT) - mu * mu + 1e-5f);
  const float4 g0 = *(const float4*)(gamma + 4 * l);
  const float4 g1 = *(const float4*)(gamma + 256 + 4 * l);
  const float4 b0 = *(const float4*)(beta + 4 * l);
  const float4 b1 = *(const float4*)(beta + 256 + 4 * l);
  va.x = (va.x - mu) * rs * g0.x + b0.x;  va.y = (va.y - mu) * rs * g0.y + b0.y;
  va.z = (va.z - mu) * rs * g0.z + b0.z;  va.w = (va.w - mu) * rs * g0.w + b0.w;
  vb.x = (vb.x - mu) * rs * g1.x + b1.x;  vb.y = (vb.y - mu) * rs * g1.y + b1.y;
  vb.z = (vb.z - mu) * rs * g1.z + b1.z;  vb.w = (vb.w - mu) * rs * g1.w + b1.w;
  *(float4*)(p + 4 * l) = va;
  *(float4*)(p + 256 + 4 * l) = vb;
}

// ----------------------------------------------------------------
extern "C" void kernel_launch(void* const* d_in, const int* in_sizes, int n_in,
                              void* d_out, int out_size, void* d_ws, size_t ws_size,
                              hipStream_t stream) {
  (void)in_sizes; (void)n_in; (void)out_size; (void)ws_size;
  const float* x = (const float*)d_in[0];
  const float* H = (const float*)d_in[1];
  const float* Wn = (const float*)d_in[2];
  const float* Wr = (const float*)d_in[3];
  const float* gamma = (const float*)d_in[4];
  const float* beta = (const float*)d_in[5];
  float* out = (float*)d_out;
  char* ws = (char*)d_ws;

  unsigned short* WT = (unsigned short*)(ws + 0);
  u64* Hb            = (u64*)(ws + 524288);
  u64* HTb           = (u64*)(ws + 13631488);
  float* inv_de      = (float*)(ws + 26738688);
  float* inv_dv      = (float*)(ws + 26759168);
  char* ximg         = (char*)(ws + 26841088);
  char* t2img        = (char*)(ws + 26841088);   // alias: live after gemmA consumed ximg
  unsigned short* partial = (unsigned short*)(ws + 37326848);
  unsigned short* T3      = (unsigned short*)(ws + 37326848);  // alias: live after reduce consumed partial

  prep_kernel<<<dim3(1024), dim3(256), 0, stream>>>(Wn, Wr, WT);
  xt_kernel<<<dim3(320, 2), dim3(256), 0, stream>>>(x, ximg);
  pack_kernel<<<dim3(320, 20), dim3(256), 0, stream>>>(H, Hb, HTb);
  deg_kernel<<<dim3(100), dim3(256), 0, stream>>>(Hb, HTb, inv_de, inv_dv);
  gemmA_kernel<<<dim3(40, 2, SPLITS), dim3(512), 0, stream>>>(ximg, HTb, partial);
  reduce_kernel<<<dim3(640), dim3(256), 0, stream>>>(partial, inv_de, t2img);
  gemmB_kernel<<<dim3(313), dim3(512), 0, stream>>>(t2img, Hb, inv_dv, T3);
  gemmC_kernel<<<dim3(157, 4), dim3(512), 0, stream>>>(x, T3, WT, out);
  ln_kernel<<<dim3(5000), dim3(256), 0, stream>>>(out, gamma, beta);
}

// Round 3
// 468.134 us; speedup vs baseline: 1.7140x; 1.2609x over previous
//
#include <hip/hip_runtime.h>

// HypergraphConv: out = LN( (H diag(1/d_e) H^T x) / d_v @ W_node + x @ W_res )
//
// Round-3: aggregation GEMMs are 1-wave (64-thr) LDS-free MFMA kernels.
// Operands live in L2: H as bitmasks (13 MB/orientation), dense side as
// pre-swizzled bf16 fragment images [k8][row]x16B (every frag load = coalesced
// 256B). Bits -> bf16 expansion in registers (12 VALU / 8 values), one per
// fragment, reused across 4 MFMAs. No barriers -> compiler emits counted
// vmcnt; explicit 2-set ping-pong prefetch hides L2 latency.
//
// Pipeline: prep(WT) | xt(x->xpb img) | pack(H->bits) -> deg ->
//   gemmA (xT@H, split2, f32 partial) -> reduceA (/d_e -> t2p img) ->
//   gemmB (H@T2 -> T3 bf16) -> gemmC ([T3|x]@WT) -> ln
//
// Workspace (bytes):
//   WT      bf16 512x512        @ 0          (524,288)
//   Hb      u64  80x20480       @ 524,288    (13,107,200)  [mw][n]
//   HTb     u64  320x5120       @ 13,631,488 (13,107,200)  [nw][m]
//   inv_de  f32  5120           @ 26,738,688 (20,480)
//   inv_dv  f32  20480          @ 26,759,168 (81,920)
//   xpb     img  2560x256x16B   @ 26,841,088 (10,485,760)
//   partial f32  2x256x5120     @ 37,326,848 (10,485,760)  [T3 bf16 aliased after reduceA]
//   t2p     img  640x256x16B    @ 47,812,608 (2,621,440)
//   total 50,434,048 (< 55,349,248 proven)

#define N_NODES 20000
#define M_EDGES 5000
#define MPAD    5120
#define NPAD    20480
#define NW      320
#define MW      80
#define DIN     256
#define DOUT    512

typedef short bf16x8 __attribute__((ext_vector_type(8)));
typedef float f32x4 __attribute__((ext_vector_type(4)));
typedef unsigned long long u64;
typedef unsigned short ushort_t;

__device__ __forceinline__ unsigned short f2b(float f) {
  unsigned u = __builtin_bit_cast(unsigned, f);
  return (unsigned short)((u + 0x7FFFu + ((u >> 16) & 1u)) >> 16);  // RNE
}

// 8 bits -> 8 bf16 {0,1}: t = b|(b<<15); pair p = ((t>>2p)&0x00010001)*0x3F80
__device__ __forceinline__ bf16x8 expand8(unsigned b) {
  union { unsigned u[4]; bf16x8 v; } r;
  const unsigned t = b | (b << 15);
  r.u[0] = (t & 0x00010001u) * 0x3F80u;
  r.u[1] = ((t >> 2) & 0x00010001u) * 0x3F80u;
  r.u[2] = ((t >> 4) & 0x00010001u) * 0x3F80u;
  r.u[3] = ((t >> 6) & 0x00010001u) * 0x3F80u;
  return r.v;
}

// ---------------------------------------------------------------- prep: WT_cat = concat(Wn,Wr)^T bf16
__global__ __launch_bounds__(256) void prep_kernel(const float* __restrict__ Wn,
                                                   const float* __restrict__ Wr,
                                                   unsigned short* __restrict__ WT) {
  const int q = blockIdx.x * 256 + threadIdx.x;  // < 262144
  const int j = q >> 9, k = q & 511;
  const float v = (k < 256) ? Wn[(size_t)k * 512 + j] : Wr[(size_t)(k - 256) * 512 + j];
  WT[(size_t)j * 512 + k] = f2b(v);
}

// ---------------------------------------------------------------- xt: x -> xpb fragment image [n8][j] x 8 bf16
__global__ __launch_bounds__(256) void xt_kernel(const float* __restrict__ x,
                                                 unsigned short* __restrict__ xpb) {
  const int j = threadIdx.x;       // 0..255
  const int n8 = blockIdx.x;       // 0..2559
  union { unsigned u[4]; bf16x8 v; } o;
#pragma unroll
  for (int p = 0; p < 4; ++p) {
    const int n = n8 * 8 + 2 * p;
    const float v0 = (n < N_NODES) ? x[(size_t)n * DIN + j] : 0.f;
    const float v1 = (n + 1 < N_NODES) ? x[(size_t)(n + 1) * DIN + j] : 0.f;
    o.u[p] = (unsigned)f2b(v0) | ((unsigned)f2b(v1) << 16);
  }
  *(bf16x8*)(xpb + ((size_t)n8 * 256 + j) * 8) = o.v;
}

// ---------------------------------------------------------------- pack: H f32 -> bitmasks, both orientations
__global__ __launch_bounds__(256) void pack_kernel(const float* __restrict__ H,
                                                   u64* __restrict__ Hb,
                                                   u64* __restrict__ HTb) {
  const int t = threadIdx.x;
  const int w = t >> 6, l = t & 63;
  const int nb = blockIdx.x;   // 0..319
  const int mb = blockIdx.y;   // 0..19
  const int m = mb * 256 + w * 64 + l;
  const bool mv = m < M_EDGES;
  unsigned lo = 0, hi = 0;
  u64 myword = 0;
#pragma unroll 8
  for (int k = 0; k < 64; ++k) {
    const int n = nb * 64 + k;
    float v = 0.f;
    if (mv && n < N_NODES) v = H[(size_t)n * M_EDGES + m];
    const bool p = (v != 0.f);
    const u64 mask = __ballot(p);
    if (l == k) myword = mask;                  // stash row-n word in lane k
    if (k < 32) lo |= (p ? 1u : 0u) << k;
    else        hi |= (p ? 1u : 0u) << (k - 32);
  }
  Hb[(size_t)(mb * 4 + w) * NPAD + nb * 64 + l] = myword;       // [mw][n]
  HTb[(size_t)nb * MPAD + m] = ((u64)hi << 32) | lo;            // [nw][m]
}

// ---------------------------------------------------------------- deg: exact popcount degrees -> reciprocals
__global__ __launch_bounds__(256) void deg_kernel(const u64* __restrict__ Hb,
                                                  const u64* __restrict__ HTb,
                                                  float* __restrict__ inv_de,
                                                  float* __restrict__ inv_dv) {
  const int g = blockIdx.x * 256 + threadIdx.x;
  if (g < MPAD) {
    int c = 0;
    for (int nw = 0; nw < NW; ++nw) c += __popcll(HTb[(size_t)nw * MPAD + g]);
    inv_de[g] = 1.f / fmaxf((float)c, 1.f);
  } else if (g < MPAD + NPAD) {
    const int n = g - MPAD;
    int c = 0;
#pragma unroll
    for (int mw = 0; mw < MW; ++mw) c += __popcll(Hb[(size_t)mw * NPAD + n]);
    inv_dv[n] = 1.f / fmaxf((float)c, 1.f);
  }
}

// ---------------------------------------------------------------- gemmA: partial[s] = x^T @ H  (64j x 64m per wave)
// 1 wave/block. A = xpb frag image, B = HT bits (reg-expanded). grid (80 m, 4 j, 2 splits)
__global__ __launch_bounds__(64) void gemmA_kernel(const unsigned short* __restrict__ xpb,
                                                   const u64* __restrict__ HTb,
                                                   float* __restrict__ partial) {
  const int l = threadIdx.x;
  const int lr = l & 15, lg = l >> 4;
  const int shl8 = lg * 8;
  const int m0 = blockIdx.x * 64;
  const int j0 = blockIdx.y * 64;
  const int s  = blockIdx.z;

  f32x4 acc[4][4] = {};
  const u64* bptr = HTb + (size_t)(s * 160) * MPAD + m0 + lr;
  const unsigned short* ap0 = xpb + ((size_t)(s * 1280 + lg)) * 2048 + (size_t)(j0 + lr) * 8;
  const unsigned short* ap1 = ap0 + 4 * 2048;

  struct F { bf16x8 a[4][2]; u64 b[4]; };
  F f0, f1;

  auto LOAD = [&](F& f, int st) {
    const u64* bp = bptr + (size_t)st * MPAD;
#pragma unroll
    for (int jg = 0; jg < 4; ++jg) f.b[jg] = bp[jg * 16];
    const unsigned short* qa0 = ap0 + (size_t)st * 16384;
    const unsigned short* qa1 = ap1 + (size_t)st * 16384;
#pragma unroll
    for (int fr = 0; fr < 4; ++fr) {
      f.a[fr][0] = *(const bf16x8*)(qa0 + fr * 128);
      f.a[fr][1] = *(const bf16x8*)(qa1 + fr * 128);
    }
  };
  auto COMP = [&](F& f) {
#pragma unroll
    for (int jg = 0; jg < 4; ++jg) {
      const unsigned wlo = (unsigned)(f.b[jg]);
      const unsigned whi = (unsigned)(f.b[jg] >> 32);
      const bf16x8 b0 = expand8((wlo >> shl8) & 255u);
      const bf16x8 b1 = expand8((whi >> shl8) & 255u);
#pragma unroll
      for (int fr = 0; fr < 4; ++fr) {
        acc[fr][jg] = __builtin_amdgcn_mfma_f32_16x16x32_bf16(f.a[fr][0], b0, acc[fr][jg], 0, 0, 0);
        acc[fr][jg] = __builtin_amdgcn_mfma_f32_16x16x32_bf16(f.a[fr][1], b1, acc[fr][jg], 0, 0, 0);
      }
    }
  };

  LOAD(f0, 0);
  for (int st = 0; st < 160; st += 2) {
    LOAD(f1, st + 1);
    COMP(f0);
    if (st + 2 < 160) LOAD(f0, st + 2);
    COMP(f1);
  }

  float* pp = partial + (size_t)s * (DIN * MPAD);
#pragma unroll
  for (int fr = 0; fr < 4; ++fr)
#pragma unroll
    for (int r = 0; r < 4; ++r) {
      const int j = j0 + fr * 16 + lg * 4 + r;
#pragma unroll
      for (int jg = 0; jg < 4; ++jg)
        pp[(size_t)j * MPAD + m0 + jg * 16 + lr] = acc[fr][jg][r];
    }
}

// ---------------------------------------------------------------- reduceA: sum splits, /d_e, emit t2p frag image [m8][j]
__global__ __launch_bounds__(256) void reduceA_kernel(const float* __restrict__ partial,
                                                      const float* __restrict__ inv_de,
                                                      unsigned short* __restrict__ t2p) {
  const int j = threadIdx.x;       // 0..255
  const int m8 = blockIdx.x;       // 0..639
  const float* p0 = partial + (size_t)j * MPAD + m8 * 8;
  const float* p1 = p0 + (size_t)DIN * MPAD;
  const f32x4 a0 = *(const f32x4*)(p0);
  const f32x4 a1 = *(const f32x4*)(p0 + 4);
  const f32x4 b0 = *(const f32x4*)(p1);
  const f32x4 b1 = *(const f32x4*)(p1 + 4);
  const f32x4 e0 = *(const f32x4*)(inv_de + m8 * 8);
  const f32x4 e1 = *(const f32x4*)(inv_de + m8 * 8 + 4);
  union { unsigned u[4]; bf16x8 v; } o;
#pragma unroll
  for (int p = 0; p < 2; ++p) {
    const float s0 = (a0[2 * p] + b0[2 * p]) * e0[2 * p];
    const float s1 = (a0[2 * p + 1] + b0[2 * p + 1]) * e0[2 * p + 1];
    o.u[p] = (unsigned)f2b(s0) | ((unsigned)f2b(s1) << 16);
    const float s2 = (a1[2 * p] + b1[2 * p]) * e1[2 * p];
    const float s3 = (a1[2 * p + 1] + b1[2 * p + 1]) * e1[2 * p + 1];
    o.u[p + 2] = (unsigned)f2b(s2) | ((unsigned)f2b(s3) << 16);
  }
  *(bf16x8*)(t2p + ((size_t)m8 * 256 + j) * 8) = o.v;
}

// ---------------------------------------------------------------- gemmB: T3 = bf16((H @ T2)/d_v)  (64n x 64j per wave)
// 1 wave/block. A = H bits (reg-expanded), B = t2p frag image. grid (313 n, 4 j)
__global__ __launch_bounds__(64) void gemmB_kernel(const unsigned short* __restrict__ t2p,
                                                   const u64* __restrict__ Hb,
                                                   const float* __restrict__ inv_dv,
                                                   unsigned short* __restrict__ T3) {
  const int l = threadIdx.x;
  const int lr = l & 15, lg = l >> 4;
  const int shl8 = lg * 8;
  const int n0 = blockIdx.x * 64;
  const int j0 = blockIdx.y * 64;

  f32x4 acc[4][4] = {};
  const u64* aptr = Hb + n0 + lr;
  const unsigned short* bp0 = t2p + (size_t)lg * 2048 + (size_t)(j0 + lr) * 8;
  const unsigned short* bp1 = bp0 + 4 * 2048;

  struct F { bf16x8 b[4][2]; u64 a[4]; };
  F f0, f1;

  auto LOAD = [&](F& f, int st) {
    const u64* ap = aptr + (size_t)st * NPAD;
#pragma unroll
    for (int fr = 0; fr < 4; ++fr) f.a[fr] = ap[fr * 16];
    const unsigned short* q0 = bp0 + (size_t)st * 16384;
    const unsigned short* q1 = bp1 + (size_t)st * 16384;
#pragma unroll
    for (int jg = 0; jg < 4; ++jg) {
      f.b[jg][0] = *(const bf16x8*)(q0 + jg * 128);
      f.b[jg][1] = *(const bf16x8*)(q1 + jg * 128);
    }
  };
  auto COMP = [&](F& f) {
#pragma unroll
    for (int fr = 0; fr < 4; ++fr) {
      const unsigned wlo = (unsigned)(f.a[fr]);
      const unsigned whi = (unsigned)(f.a[fr] >> 32);
      const bf16x8 a0 = expand8((wlo >> shl8) & 255u);
      const bf16x8 a1 = expand8((whi >> shl8) & 255u);
#pragma unroll
      for (int jg = 0; jg < 4; ++jg) {
        acc[fr][jg] = __builtin_amdgcn_mfma_f32_16x16x32_bf16(a0, f.b[jg][0], acc[fr][jg], 0, 0, 0);
        acc[fr][jg] = __builtin_amdgcn_mfma_f32_16x16x32_bf16(a1, f.b[jg][1], acc[fr][jg], 0, 0, 0);
      }
    }
  };

  LOAD(f0, 0);
  for (int st = 0; st < 80; st += 2) {
    LOAD(f1, st + 1);
    COMP(f0);
    if (st + 2 < 80) LOAD(f0, st + 2);
    COMP(f1);
  }

#pragma unroll
  for (int fr = 0; fr < 4; ++fr) {
    const f32x4 dv = *(const f32x4*)(inv_dv + n0 + fr * 16 + lg * 4);
#pragma unroll
    for (int r = 0; r < 4; ++r) {
      const int n = n0 + fr * 16 + lg * 4 + r;
      if (n < N_NODES) {
#pragma unroll
        for (int jg = 0; jg < 4; ++jg)
          T3[(size_t)n * DIN + j0 + jg * 16 + lr] = f2b(acc[fr][jg][r] * dv[r]);
      }
    }
  }
}

// ---------------------------------------------------------------- gemmC: out = [T3 | x] @ WT_cat (f32)
__global__ __launch_bounds__(512) void gemmC_kernel(const float* __restrict__ x,
                                                    const unsigned short* __restrict__ T3,
                                                    const unsigned short* __restrict__ WT,
                                                    float* __restrict__ out) {
  __shared__ unsigned short As[128 * 64];
  __shared__ unsigned short Bsh[128 * 64];
  const int t = threadIdx.x;
  const int n0 = blockIdx.x * 128;
  const int j0 = blockIdx.y * 128;
  const int w = t >> 6, l = t & 63;
  const int wr = w >> 2, wc = w & 3;
  const int lr = l & 15, lg = l >> 4;
  f32x4 acc[4][2];
#pragma unroll
  for (int i = 0; i < 4; ++i)
#pragma unroll
    for (int jq = 0; jq < 2; ++jq) acc[i][jq] = (f32x4){0.f, 0.f, 0.f, 0.f};
  const int sr = t >> 3, sk8 = t & 7;

  for (int st = 0; st < 8; ++st) {
    __syncthreads();
#pragma unroll
    for (int p = 0; p < 2; ++p) {  // stage A: k<256 from T3 (bf16), k>=256 from x (f32)
      const int node = sr + p * 64;
      const int gn = n0 + node;
      bf16x8 pk;
      if (st < 4) {
        if (gn < N_NODES)
          pk = *(const bf16x8*)(T3 + (size_t)gn * DIN + st * 64 + sk8 * 8);
        else {
#pragma unroll
          for (int jq = 0; jq < 8; ++jq) pk[jq] = 0;
        }
      } else {
        if (gn < N_NODES) {
          const float4* p4 = (const float4*)(x + (size_t)gn * DIN + (st - 4) * 64 + sk8 * 8);
          const float4 q0 = p4[0], q1 = p4[1];
          pk[0] = (short)f2b(q0.x); pk[1] = (short)f2b(q0.y); pk[2] = (short)f2b(q0.z); pk[3] = (short)f2b(q0.w);
          pk[4] = (short)f2b(q1.x); pk[5] = (short)f2b(q1.y); pk[6] = (short)f2b(q1.z); pk[7] = (short)f2b(q1.w);
        } else {
#pragma unroll
          for (int jq = 0; jq < 8; ++jq) pk[jq] = 0;
        }
      }
      *(bf16x8*)((char*)As + node * 128 + ((sk8 * 16) ^ ((node & 7) << 4))) = pk;
    }
#pragma unroll
    for (int p = 0; p < 2; ++p) {  // stage B: WT rows
      const int j = sr + p * 64;
      const bf16x8 pk = *(const bf16x8*)(WT + (size_t)(j0 + j) * 512 + st * 64 + sk8 * 8);
      *(bf16x8*)((char*)Bsh + j * 128 + ((sk8 * 16) ^ ((j & 7) << 4))) = pk;
    }
    __syncthreads();
#pragma unroll
    for (int ks = 0; ks < 2; ++ks) {
      const int kb = ks * 64 + 16 * lg;
      bf16x8 bf[2];
#pragma unroll
      for (int fc = 0; fc < 2; ++fc) {
        const int row = wc * 32 + fc * 16 + lr;
        bf[fc] = *(const bf16x8*)((const char*)Bsh + row * 128 + (kb ^ ((row & 7) << 4)));
      }
#pragma unroll
      for (int fr = 0; fr < 4; ++fr) {
        const int row = wr * 64 + fr * 16 + lr;
        const bf16x8 af = *(const bf16x8*)((const char*)As + row * 128 + (kb ^ ((row & 7) << 4)));
#pragma unroll
        for (int fc = 0; fc < 2; ++fc)
          acc[fr][fc] = __builtin_amdgcn_mfma_f32_16x16x32_bf16(af, bf[fc], acc[fr][fc], 0, 0, 0);
      }
    }
  }
#pragma unroll
  for (int fr = 0; fr < 4; ++fr)
#pragma unroll
    for (int fc = 0; fc < 2; ++fc) {
      const int col = j0 + wc * 32 + fc * 16 + lr;
#pragma unroll
      for (int r = 0; r < 4; ++r) {
        const int row = n0 + wr * 64 + fr * 16 + 4 * lg + r;
        if (row < N_NODES) out[(size_t)row * DOUT + col] = acc[fr][fc][r];
      }
    }
}

// ---------------------------------------------------------------- LayerNorm (in place on out)
__global__ __launch_bounds__(256) void ln_kernel(float* __restrict__ out,
                                                 const float* __restrict__ gamma,
                                                 const float* __restrict__ beta) {
  const int row = blockIdx.x * 4 + (threadIdx.x >> 6);
  const int l = threadIdx.x & 63;
  float* p = out + (size_t)row * DOUT;
  float4 va = *(const float4*)(p + 4 * l);
  float4 vb = *(const float4*)(p + 256 + 4 * l);
  float s = va.x + va.y + va.z + va.w + vb.x + vb.y + vb.z + vb.w;
  float s2 = va.x * va.x + va.y * va.y + va.z * va.z + va.w * va.w +
             vb.x * vb.x + vb.y * vb.y + vb.z * vb.z + vb.w * vb.w;
#pragma unroll
  for (int m = 1; m < 64; m <<= 1) { s += __shfl_xor(s, m, 64); s2 += __shfl_xor(s2, m, 64); }
  const float mu = s * (1.f / DOUT);
  const float rs = rsqrtf(s2 * (1.f / DOUT) - mu * mu + 1e-5f);
  const float4 g0 = *(const float4*)(gamma + 4 * l);
  const float4 g1 = *(const float4*)(gamma + 256 + 4 * l);
  const float4 b0 = *(const float4*)(beta + 4 * l);
  const float4 b1 = *(const float4*)(beta + 256 + 4 * l);
  va.x = (va.x - mu) * rs * g0.x + b0.x;  va.y = (va.y - mu) * rs * g0.y + b0.y;
  va.z = (va.z - mu) * rs * g0.z + b0.z;  va.w = (va.w - mu) * rs * g0.w + b0.w;
  vb.x = (vb.x - mu) * rs * g1.x + b1.x;  vb.y = (vb.y - mu) * rs * g1.y + b1.y;
  vb.z = (vb.z - mu) * rs * g1.z + b1.z;  vb.w = (vb.w - mu) * rs * g1.w + b1.w;
  *(float4*)(p + 4 * l) = va;
  *(float4*)(p + 256 + 4 * l) = vb;
}

// ----------------------------------------------------------------
extern "C" void kernel_launch(void* const* d_in, const int* in_sizes, int n_in,
                              void* d_out, int out_size, void* d_ws, size_t ws_size,
                              hipStream_t stream) {
  (void)in_sizes; (void)n_in; (void)out_size; (void)ws_size;
  const float* x = (const float*)d_in[0];
  const float* H = (const float*)d_in[1];
  const float* Wn = (const float*)d_in[2];
  const float* Wr = (const float*)d_in[3];
  const float* gamma = (const float*)d_in[4];
  const float* beta = (const float*)d_in[5];
  float* out = (float*)d_out;
  char* ws = (char*)d_ws;

  unsigned short* WT  = (unsigned short*)(ws + 0);
  u64* Hb             = (u64*)(ws + 524288);
  u64* HTb            = (u64*)(ws + 13631488);
  float* inv_de       = (float*)(ws + 26738688);
  float* inv_dv       = (float*)(ws + 26759168);
  unsigned short* xpb = (unsigned short*)(ws + 26841088);
  float* partial      = (float*)(ws + 37326848);
  unsigned short* T3  = (unsigned short*)(ws + 37326848);  // alias: live after reduceA consumed partial
  unsigned short* t2p = (unsigned short*)(ws + 47812608);

  prep_kernel<<<dim3(1024), dim3(256), 0, stream>>>(Wn, Wr, WT);
  xt_kernel<<<dim3(2560), dim3(256), 0, stream>>>(x, xpb);
  pack_kernel<<<dim3(320, 20), dim3(256), 0, stream>>>(H, Hb, HTb);
  deg_kernel<<<dim3(100), dim3(256), 0, stream>>>(Hb, HTb, inv_de, inv_dv);
  gemmA_kernel<<<dim3(80, 4, 2), dim3(64), 0, stream>>>(xpb, HTb, partial);
  reduceA_kernel<<<dim3(640), dim3(256), 0, stream>>>(partial, inv_de, t2p);
  gemmB_kernel<<<dim3(313, 4), dim3(64), 0, stream>>>(t2p, Hb, inv_dv, T3);
  gemmC_kernel<<<dim3(157, 4), dim3(512), 0, stream>>>(x, T3, WT, out);
  ln_kernel<<<dim3(5000), dim3(256), 0, stream>>>(out, gamma, beta);
}

// Round 4
// 426.276 us; speedup vs baseline: 1.8823x; 1.0982x over previous
//
#include <hip/hip_runtime.h>

// HypergraphConv: out = LN( (H diag(1/d_e) H^T x) / d_v @ W_node + x @ W_res )
//
// Round-4: aggregation GEMMs are 4-wave (256-thr) LDS-free MFMA kernels;
// waves share the dense-operand slice (same addresses -> L1 reuse) and own
// private 64x64 output tiles. Ping-pong prefetch uses NAMED registers via
// macros (no struct/lambda -> no scratch risk), same-acc MFMAs 4 apart.
// H lives as bitmasks (13 MB/orientation); bits -> bf16 in registers.
//
// Pipeline: prep(WT) | xt(x->xpb img) | pack(H->bits) -> deg ->
//   gemmA (xT@H, split4, f32 partial) -> reduceA (/d_e -> t2p img) ->
//   gemmB (H@T2 -> T3 bf16) -> gemmC ([T3|x]@WT) -> ln
//
// Workspace (bytes, ws_size ~1.6GB per harness fill evidence):
//   WT      bf16 512x512        @ 0          (524,288)
//   Hb      u64  80x20480       @ 524,288    (13,107,200)  [mw][n]
//   HTb     u64  320x5120       @ 13,631,488 (13,107,200)  [nw][m]
//   inv_de  f32  5120           @ 26,738,688 (20,480)
//   inv_dv  f32  20480          @ 26,759,168 (81,920)
//   xpb     img  2560x256x16B   @ 26,841,088 (10,485,760)
//   partial f32  4x256x5120     @ 37,326,848 (20,971,520)  [T3 bf16 aliased after reduceA]
//   t2p     img  640x256x16B    @ 58,298,368 (2,621,440)
//   total 60,919,808

#define N_NODES 20000
#define M_EDGES 5000
#define MPAD    5120
#define NPAD    20480
#define NW      320
#define MW      80
#define DIN     256
#define DOUT    512
#define SPLITS  4

typedef short bf16x8 __attribute__((ext_vector_type(8)));
typedef float f32x4 __attribute__((ext_vector_type(4)));
typedef unsigned long long u64;

#define MFMA16(A, B, C) __builtin_amdgcn_mfma_f32_16x16x32_bf16((A), (B), (C), 0, 0, 0)

__device__ __forceinline__ unsigned short f2b(float f) {
  unsigned u = __builtin_bit_cast(unsigned, f);
  return (unsigned short)((u + 0x7FFFu + ((u >> 16) & 1u)) >> 16);  // RNE
}

// 8 bits -> 8 bf16 {0,1}: t = b|(b<<15); pair p = ((t>>2p)&0x00010001)*0x3F80
__device__ __forceinline__ bf16x8 expand8(unsigned b) {
  union { unsigned u[4]; bf16x8 v; } r;
  const unsigned t = b | (b << 15);
  r.u[0] = (t & 0x00010001u) * 0x3F80u;
  r.u[1] = ((t >> 2) & 0x00010001u) * 0x3F80u;
  r.u[2] = ((t >> 4) & 0x00010001u) * 0x3F80u;
  r.u[3] = ((t >> 6) & 0x00010001u) * 0x3F80u;
  return r.v;
}

// ---------------------------------------------------------------- prep: WT_cat = concat(Wn,Wr)^T bf16
__global__ __launch_bounds__(256) void prep_kernel(const float* __restrict__ Wn,
                                                   const float* __restrict__ Wr,
                                                   unsigned short* __restrict__ WT) {
  const int q = blockIdx.x * 256 + threadIdx.x;  // < 262144
  const int j = q >> 9, k = q & 511;
  const float v = (k < 256) ? Wn[(size_t)k * 512 + j] : Wr[(size_t)(k - 256) * 512 + j];
  WT[(size_t)j * 512 + k] = f2b(v);
}

// ---------------------------------------------------------------- xt: x -> xpb fragment image [n8][j] x 8 bf16
__global__ __launch_bounds__(256) void xt_kernel(const float* __restrict__ x,
                                                 unsigned short* __restrict__ xpb) {
  const int j = threadIdx.x;       // 0..255
  const int n8 = blockIdx.x;       // 0..2559
  union { unsigned u[4]; bf16x8 v; } o;
#pragma unroll
  for (int p = 0; p < 4; ++p) {
    const int n = n8 * 8 + 2 * p;
    const float v0 = (n < N_NODES) ? x[(size_t)n * DIN + j] : 0.f;
    const float v1 = (n + 1 < N_NODES) ? x[(size_t)(n + 1) * DIN + j] : 0.f;
    o.u[p] = (unsigned)f2b(v0) | ((unsigned)f2b(v1) << 16);
  }
  *(bf16x8*)(xpb + ((size_t)n8 * 256 + j) * 8) = o.v;
}

// ---------------------------------------------------------------- pack: H f32 -> bitmasks, both orientations
__global__ __launch_bounds__(256) void pack_kernel(const float* __restrict__ H,
                                                   u64* __restrict__ Hb,
                                                   u64* __restrict__ HTb) {
  const int t = threadIdx.x;
  const int w = t >> 6, l = t & 63;
  const int nb = blockIdx.x;   // 0..319
  const int mb = blockIdx.y;   // 0..19
  const int m = mb * 256 + w * 64 + l;
  const bool mv = m < M_EDGES;
  unsigned lo = 0, hi = 0;
  u64 myword = 0;
#pragma unroll 8
  for (int k = 0; k < 64; ++k) {
    const int n = nb * 64 + k;
    float v = 0.f;
    if (mv && n < N_NODES) v = H[(size_t)n * M_EDGES + m];
    const bool p = (v != 0.f);
    const u64 mask = __ballot(p);
    if (l == k) myword = mask;                  // stash row-n word in lane k
    if (k < 32) lo |= (p ? 1u : 0u) << k;
    else        hi |= (p ? 1u : 0u) << (k - 32);
  }
  Hb[(size_t)(mb * 4 + w) * NPAD + nb * 64 + l] = myword;       // [mw][n]
  HTb[(size_t)nb * MPAD + m] = ((u64)hi << 32) | lo;            // [nw][m]
}

// ---------------------------------------------------------------- deg: exact popcount degrees -> reciprocals
__global__ __launch_bounds__(256) void deg_kernel(const u64* __restrict__ Hb,
                                                  const u64* __restrict__ HTb,
                                                  float* __restrict__ inv_de,
                                                  float* __restrict__ inv_dv) {
  const int g = blockIdx.x * 256 + threadIdx.x;
  if (g < MPAD) {
    int c = 0;
    for (int nw = 0; nw < NW; ++nw) c += __popcll(HTb[(size_t)nw * MPAD + g]);
    inv_de[g] = 1.f / fmaxf((float)c, 1.f);
  } else if (g < MPAD + NPAD) {
    const int n = g - MPAD;
    int c = 0;
#pragma unroll
    for (int mw = 0; mw < MW; ++mw) c += __popcll(Hb[(size_t)mw * NPAD + n]);
    inv_dv[n] = 1.f / fmaxf((float)c, 1.f);
  }
}

// ---------------------------------------------------------------- gemmA: partial[s] = x^T @ H
// 4 waves/block, wave-private 64j x 64m tiles (same j0 -> shared A slice via L1).
// grid (20 m-chunks, 4 j, 4 splits). A = xpb frag image, B = HT bits (reg-expanded).
__global__ __launch_bounds__(256) void gemmA_kernel(const unsigned short* __restrict__ xpb,
                                                    const u64* __restrict__ HTb,
                                                    float* __restrict__ partial) {
  const int t = threadIdx.x;
  const int wv = t >> 6, l = t & 63;
  const int lr = l & 15, lg = l >> 4;
  const int shl8 = lg * 8;
  const int m0 = blockIdx.x * 256 + wv * 64;
  const int j0 = blockIdx.y * 64;
  const int s  = blockIdx.z;

  f32x4 acc[4][4] = {};
  const u64* bptr = HTb + (size_t)(s * 80) * MPAD + m0 + lr;
  const unsigned short* ap0 = xpb + ((size_t)(s * 640 + lg)) * 2048 + (size_t)(j0 + lr) * 8;
  const unsigned short* ap1 = ap0 + 4 * 2048;

  bf16x8 a00, a01, a02, a03, a04, a05, a06, a07;
  bf16x8 a10, a11, a12, a13, a14, a15, a16, a17;
  u64 b00, b01, b02, b03, b10, b11, b12, b13;

#define GA_LOAD(S, st_) do {                                                   \
    const u64* bp_ = bptr + (size_t)(st_) * MPAD;                              \
    b##S##0 = bp_[0];  b##S##1 = bp_[16]; b##S##2 = bp_[32]; b##S##3 = bp_[48];\
    const unsigned short* q0_ = ap0 + (size_t)(st_) * 16384;                   \
    const unsigned short* q1_ = ap1 + (size_t)(st_) * 16384;                   \
    a##S##0 = *(const bf16x8*)(q0_);       a##S##1 = *(const bf16x8*)(q0_ + 128); \
    a##S##2 = *(const bf16x8*)(q0_ + 256); a##S##3 = *(const bf16x8*)(q0_ + 384); \
    a##S##4 = *(const bf16x8*)(q1_);       a##S##5 = *(const bf16x8*)(q1_ + 128); \
    a##S##6 = *(const bf16x8*)(q1_ + 256); a##S##7 = *(const bf16x8*)(q1_ + 384); \
  } while (0)

#define GA_JG(S, jg, BW) do {                                                  \
    const unsigned wlo_ = (unsigned)(BW), whi_ = (unsigned)((BW) >> 32);       \
    const bf16x8 e0_ = expand8((wlo_ >> shl8) & 255u);                         \
    const bf16x8 e1_ = expand8((whi_ >> shl8) & 255u);                         \
    acc[0][jg] = MFMA16(a##S##0, e0_, acc[0][jg]);                             \
    acc[1][jg] = MFMA16(a##S##1, e0_, acc[1][jg]);                             \
    acc[2][jg] = MFMA16(a##S##2, e0_, acc[2][jg]);                             \
    acc[3][jg] = MFMA16(a##S##3, e0_, acc[3][jg]);                             \
    acc[0][jg] = MFMA16(a##S##4, e1_, acc[0][jg]);                             \
    acc[1][jg] = MFMA16(a##S##5, e1_, acc[1][jg]);                             \
    acc[2][jg] = MFMA16(a##S##6, e1_, acc[2][jg]);                             \
    acc[3][jg] = MFMA16(a##S##7, e1_, acc[3][jg]);                             \
  } while (0)

#define GA_COMP(S) do { GA_JG(S, 0, b##S##0); GA_JG(S, 1, b##S##1);            \
                        GA_JG(S, 2, b##S##2); GA_JG(S, 3, b##S##3); } while (0)

  GA_LOAD(0, 0);
  for (int st = 0; st < 80; st += 2) {
    GA_LOAD(1, st + 1);
    GA_COMP(0);
    if (st + 2 < 80) GA_LOAD(0, st + 2);
    GA_COMP(1);
  }
#undef GA_LOAD
#undef GA_JG
#undef GA_COMP

  float* pp = partial + (size_t)s * (DIN * MPAD);
#pragma unroll
  for (int fr = 0; fr < 4; ++fr)
#pragma unroll
    for (int r = 0; r < 4; ++r) {
      const int j = j0 + fr * 16 + lg * 4 + r;
#pragma unroll
      for (int jg = 0; jg < 4; ++jg)
        pp[(size_t)j * MPAD + m0 + jg * 16 + lr] = acc[fr][jg][r];
    }
}

// ---------------------------------------------------------------- reduceA: sum splits, /d_e, emit t2p frag image [m8][j]
__global__ __launch_bounds__(256) void reduceA_kernel(const float* __restrict__ partial,
                                                      const float* __restrict__ inv_de,
                                                      unsigned short* __restrict__ t2p) {
  const int j = threadIdx.x;       // 0..255
  const int m8 = blockIdx.x;       // 0..639
  const float* p0 = partial + (size_t)j * MPAD + m8 * 8;
  f32x4 s0 = (f32x4){0.f, 0.f, 0.f, 0.f}, s1 = s0;
#pragma unroll
  for (int sp = 0; sp < SPLITS; ++sp) {
    const float* p = p0 + (size_t)sp * (DIN * MPAD);
    const f32x4 a0 = *(const f32x4*)(p);
    const f32x4 a1 = *(const f32x4*)(p + 4);
#pragma unroll
    for (int i = 0; i < 4; ++i) { s0[i] += a0[i]; s1[i] += a1[i]; }
  }
  const f32x4 e0 = *(const f32x4*)(inv_de + m8 * 8);
  const f32x4 e1 = *(const f32x4*)(inv_de + m8 * 8 + 4);
  union { unsigned u[4]; bf16x8 v; } o;
#pragma unroll
  for (int p = 0; p < 2; ++p) {
    o.u[p]     = (unsigned)f2b(s0[2 * p] * e0[2 * p]) | ((unsigned)f2b(s0[2 * p + 1] * e0[2 * p + 1]) << 16);
    o.u[p + 2] = (unsigned)f2b(s1[2 * p] * e1[2 * p]) | ((unsigned)f2b(s1[2 * p + 1] * e1[2 * p + 1]) << 16);
  }
  *(bf16x8*)(t2p + ((size_t)m8 * 256 + j) * 8) = o.v;
}

// ---------------------------------------------------------------- gemmB: T3 = bf16((H @ T2)/d_v)
// 4 waves/block, wave-private 64n x 64j tiles (same j0 -> shared B slice via L1).
// grid (79 n-chunks, 4 j). A = H bits (reg-expanded), B = t2p frag image.
__global__ __launch_bounds__(256) void gemmB_kernel(const unsigned short* __restrict__ t2p,
                                                    const u64* __restrict__ Hb,
                                                    const float* __restrict__ inv_dv,
                                                    unsigned short* __restrict__ T3) {
  const int t = threadIdx.x;
  const int wv = t >> 6, l = t & 63;
  const int lr = l & 15, lg = l >> 4;
  const int shl8 = lg * 8;
  const int n0 = blockIdx.x * 256 + wv * 64;
  const int j0 = blockIdx.y * 64;

  f32x4 acc[4][4] = {};
  const u64* aptr = Hb + n0 + lr;
  const unsigned short* bp0 = t2p + (size_t)lg * 2048 + (size_t)(j0 + lr) * 8;
  const unsigned short* bp1 = bp0 + 4 * 2048;

  u64 a00, a01, a02, a03, a10, a11, a12, a13;
  bf16x8 b00, b01, b02, b03, b04, b05, b06, b07;
  bf16x8 b10, b11, b12, b13, b14, b15, b16, b17;

#define GB_LOAD(S, st_) do {                                                   \
    const u64* ap_ = aptr + (size_t)(st_) * NPAD;                              \
    a##S##0 = ap_[0];  a##S##1 = ap_[16]; a##S##2 = ap_[32]; a##S##3 = ap_[48];\
    const unsigned short* q0_ = bp0 + (size_t)(st_) * 16384;                   \
    const unsigned short* q1_ = bp1 + (size_t)(st_) * 16384;                   \
    b##S##0 = *(const bf16x8*)(q0_);       b##S##1 = *(const bf16x8*)(q0_ + 128); \
    b##S##2 = *(const bf16x8*)(q0_ + 256); b##S##3 = *(const bf16x8*)(q0_ + 384); \
    b##S##4 = *(const bf16x8*)(q1_);       b##S##5 = *(const bf16x8*)(q1_ + 128); \
    b##S##6 = *(const bf16x8*)(q1_ + 256); b##S##7 = *(const bf16x8*)(q1_ + 384); \
  } while (0)

#define GB_FR(S, fr, AW) do {                                                  \
    const unsigned wlo_ = (unsigned)(AW), whi_ = (unsigned)((AW) >> 32);       \
    const bf16x8 e0_ = expand8((wlo_ >> shl8) & 255u);                         \
    const bf16x8 e1_ = expand8((whi_ >> shl8) & 255u);                         \
    acc[fr][0] = MFMA16(e0_, b##S##0, acc[fr][0]);                             \
    acc[fr][1] = MFMA16(e0_, b##S##1, acc[fr][1]);                             \
    acc[fr][2] = MFMA16(e0_, b##S##2, acc[fr][2]);                             \
    acc[fr][3] = MFMA16(e0_, b##S##3, acc[fr][3]);                             \
    acc[fr][0] = MFMA16(e1_, b##S##4, acc[fr][0]);                             \
    acc[fr][1] = MFMA16(e1_, b##S##5, acc[fr][1]);                             \
    acc[fr][2] = MFMA16(e1_, b##S##6, acc[fr][2]);                             \
    acc[fr][3] = MFMA16(e1_, b##S##7, acc[fr][3]);                             \
  } while (0)

#define GB_COMP(S) do { GB_FR(S, 0, a##S##0); GB_FR(S, 1, a##S##1);            \
                        GB_FR(S, 2, a##S##2); GB_FR(S, 3, a##S##3); } while (0)

  GB_LOAD(0, 0);
  for (int st = 0; st < 80; st += 2) {
    GB_LOAD(1, st + 1);
    GB_COMP(0);
    if (st + 2 < 80) GB_LOAD(0, st + 2);
    GB_COMP(1);
  }
#undef GB_LOAD
#undef GB_FR
#undef GB_COMP

#pragma unroll
  for (int fr = 0; fr < 4; ++fr) {
    const f32x4 dv = *(const f32x4*)(inv_dv + n0 + fr * 16 + lg * 4);
#pragma unroll
    for (int r = 0; r < 4; ++r) {
      const int n = n0 + fr * 16 + lg * 4 + r;
      if (n < N_NODES) {
#pragma unroll
        for (int jg = 0; jg < 4; ++jg)
          T3[(size_t)n * DIN + j0 + jg * 16 + lr] = f2b(acc[fr][jg][r] * dv[r]);
      }
    }
  }
}

// ---------------------------------------------------------------- gemmC: out = [T3 | x] @ WT_cat (f32)
__global__ __launch_bounds__(512) void gemmC_kernel(const float* __restrict__ x,
                                                    const unsigned short* __restrict__ T3,
                                                    const unsigned short* __restrict__ WT,
                                                    float* __restrict__ out) {
  __shared__ unsigned short As[128 * 64];
  __shared__ unsigned short Bsh[128 * 64];
  const int t = threadIdx.x;
  const int n0 = blockIdx.x * 128;
  const int j0 = blockIdx.y * 128;
  const int w = t >> 6, l = t & 63;
  const int wr = w >> 2, wc = w & 3;
  const int lr = l & 15, lg = l >> 4;
  f32x4 acc[4][2];
#pragma unroll
  for (int i = 0; i < 4; ++i)
#pragma unroll
    for (int jq = 0; jq < 2; ++jq) acc[i][jq] = (f32x4){0.f, 0.f, 0.f, 0.f};
  const int sr = t >> 3, sk8 = t & 7;

  for (int st = 0; st < 8; ++st) {
    __syncthreads();
#pragma unroll
    for (int p = 0; p < 2; ++p) {  // stage A: k<256 from T3 (bf16), k>=256 from x (f32)
      const int node = sr + p * 64;
      const int gn = n0 + node;
      bf16x8 pk;
      if (st < 4) {
        if (gn < N_NODES)
          pk = *(const bf16x8*)(T3 + (size_t)gn * DIN + st * 64 + sk8 * 8);
        else {
#pragma unroll
          for (int jq = 0; jq < 8; ++jq) pk[jq] = 0;
        }
      } else {
        if (gn < N_NODES) {
          const float4* p4 = (const float4*)(x + (size_t)gn * DIN + (st - 4) * 64 + sk8 * 8);
          const float4 q0 = p4[0], q1 = p4[1];
          pk[0] = (short)f2b(q0.x); pk[1] = (short)f2b(q0.y); pk[2] = (short)f2b(q0.z); pk[3] = (short)f2b(q0.w);
          pk[4] = (short)f2b(q1.x); pk[5] = (short)f2b(q1.y); pk[6] = (short)f2b(q1.z); pk[7] = (short)f2b(q1.w);
        } else {
#pragma unroll
          for (int jq = 0; jq < 8; ++jq) pk[jq] = 0;
        }
      }
      *(bf16x8*)((char*)As + node * 128 + ((sk8 * 16) ^ ((node & 7) << 4))) = pk;
    }
#pragma unroll
    for (int p = 0; p < 2; ++p) {  // stage B: WT rows
      const int j = sr + p * 64;
      const bf16x8 pk = *(const bf16x8*)(WT + (size_t)(j0 + j) * 512 + st * 64 + sk8 * 8);
      *(bf16x8*)((char*)Bsh + j * 128 + ((sk8 * 16) ^ ((j & 7) << 4))) = pk;
    }
    __syncthreads();
#pragma unroll
    for (int ks = 0; ks < 2; ++ks) {
      const int kb = ks * 64 + 16 * lg;
      bf16x8 bf[2];
#pragma unroll
      for (int fc = 0; fc < 2; ++fc) {
        const int row = wc * 32 + fc * 16 + lr;
        bf[fc] = *(const bf16x8*)((const char*)Bsh + row * 128 + (kb ^ ((row & 7) << 4)));
      }
#pragma unroll
      for (int fr = 0; fr < 4; ++fr) {
        const int row = wr * 64 + fr * 16 + lr;
        const bf16x8 af = *(const bf16x8*)((const char*)As + row * 128 + (kb ^ ((row & 7) << 4)));
#pragma unroll
        for (int fc = 0; fc < 2; ++fc)
          acc[fr][fc] = __builtin_amdgcn_mfma_f32_16x16x32_bf16(af, bf[fc], acc[fr][fc], 0, 0, 0);
      }
    }
  }
#pragma unroll
  for (int fr = 0; fr < 4; ++fr)
#pragma unroll
    for (int fc = 0; fc < 2; ++fc) {
      const int col = j0 + wc * 32 + fc * 16 + lr;
#pragma unroll
      for (int r = 0; r < 4; ++r) {
        const int row = n0 + wr * 64 + fr * 16 + 4 * lg + r;
        if (row < N_NODES) out[(size_t)row * DOUT + col] = acc[fr][fc][r];
      }
    }
}

// ---------------------------------------------------------------- LayerNorm (in place on out)
__global__ __launch_bounds__(256) void ln_kernel(float* __restrict__ out,
                                                 const float* __restrict__ gamma,
                                                 const float* __restrict__ beta) {
  const int row = blockIdx.x * 4 + (threadIdx.x >> 6);
  const int l = threadIdx.x & 63;
  float* p = out + (size_t)row * DOUT;
  float4 va = *(const float4*)(p + 4 * l);
  float4 vb = *(const float4*)(p + 256 + 4 * l);
  float s = va.x + va.y + va.z + va.w + vb.x + vb.y + vb.z + vb.w;
  float s2 = va.x * va.x + va.y * va.y + va.z * va.z + va.w * va.w +
             vb.x * vb.x + vb.y * vb.y + vb.z * vb.z + vb.w * vb.w;
#pragma unroll
  for (int m = 1; m < 64; m <<= 1) { s += __shfl_xor(s, m, 64); s2 += __shfl_xor(s2, m, 64); }
  const float mu = s * (1.f / DOUT);
  const float rs = rsqrtf(s2 * (1.f / DOUT) - mu * mu + 1e-5f);
  const float4 g0 = *(const float4*)(gamma + 4 * l);
  const float4 g1 = *(const float4*)(gamma + 256 + 4 * l);
  const float4 b0 = *(const float4*)(beta + 4 * l);
  const float4 b1 = *(const float4*)(beta + 256 + 4 * l);
  va.x = (va.x - mu) * rs * g0.x + b0.x;  va.y = (va.y - mu) * rs * g0.y + b0.y;
  va.z = (va.z - mu) * rs * g0.z + b0.z;  va.w = (va.w - mu) * rs * g0.w + b0.w;
  vb.x = (vb.x - mu) * rs * g1.x + b1.x;  vb.y = (vb.y - mu) * rs * g1.y + b1.y;
  vb.z = (vb.z - mu) * rs * g1.z + b1.z;  vb.w = (vb.w - mu) * rs * g1.w + b1.w;
  *(float4*)(p + 4 * l) = va;
  *(float4*)(p + 256 + 4 * l) = vb;
}

// ----------------------------------------------------------------
extern "C" void kernel_launch(void* const* d_in, const int* in_sizes, int n_in,
                              void* d_out, int out_size, void* d_ws, size_t ws_size,
                              hipStream_t stream) {
  (void)in_sizes; (void)n_in; (void)out_size; (void)ws_size;
  const float* x = (const float*)d_in[0];
  const float* H = (const float*)d_in[1];
  const float* Wn = (const float*)d_in[2];
  const float* Wr = (const float*)d_in[3];
  const float* gamma = (const float*)d_in[4];
  const float* beta = (const float*)d_in[5];
  float* out = (float*)d_out;
  char* ws = (char*)d_ws;

  unsigned short* WT  = (unsigned short*)(ws + 0);
  u64* Hb             = (u64*)(ws + 524288);
  u64* HTb            = (u64*)(ws + 13631488);
  float* inv_de       = (float*)(ws + 26738688);
  float* inv_dv       = (float*)(ws + 26759168);
  unsigned short* xpb = (unsigned short*)(ws + 26841088);
  float* partial      = (float*)(ws + 37326848);
  unsigned short* T3  = (unsigned short*)(ws + 37326848);  // alias: live after reduceA consumed partial
  unsigned short* t2p = (unsigned short*)(ws + 58298368);

  prep_kernel<<<dim3(1024), dim3(256), 0, stream>>>(Wn, Wr, WT);
  xt_kernel<<<dim3(2560), dim3(256), 0, stream>>>(x, xpb);
  pack_kernel<<<dim3(320, 20), dim3(256), 0, stream>>>(H, Hb, HTb);
  deg_kernel<<<dim3(100), dim3(256), 0, stream>>>(Hb, HTb, inv_de, inv_dv);
  gemmA_kernel<<<dim3(20, 4, SPLITS), dim3(256), 0, stream>>>(xpb, HTb, partial);
  reduceA_kernel<<<dim3(640), dim3(256), 0, stream>>>(partial, inv_de, t2p);
  gemmB_kernel<<<dim3(79, 4), dim3(256), 0, stream>>>(t2p, Hb, inv_dv, T3);
  gemmC_kernel<<<dim3(157, 4), dim3(512), 0, stream>>>(x, T3, WT, out);
  ln_kernel<<<dim3(5000), dim3(256), 0, stream>>>(out, gamma, beta);
}

// Round 5
// 396.913 us; speedup vs baseline: 2.0216x; 1.0740x over previous
//
#include <hip/hip_runtime.h>

// HypergraphConv: out = LN( (H diag(1/d_e) H^T x) / d_v @ W_node + x @ W_res )
//
// Round-5: aggregation GEMMs = 4-wave blocks, LDS-staged dense operand via
// global_load_lds into FRAG-CONTIGUOUS layout ([frag][lane]x16B -> ds_read_b128
// reads 1 contiguous KB, conflict-free), H-bits register-ping-pong (expand in
// regs), 2-barrier/step pipeline with counted vmcnt(6) (round-2-proven sync).
// 1-D grids put blocks sharing a dense slice on one XCD (wgid%8 round-robin).
// reduceA rewritten coalesced (m on threads, not j).
//
// Workspace (bytes), no aliasing:
//   WT       bf16 512x512      @ 0          (524,288)
//   Hb       u64  80x20480     @ 524,288    (13,107,200)  [mw][n]
//   HTb      u64  320x5120     @ 13,631,488 (13,107,200)  [nw][m]
//   inv_de   f32  5120         @ 26,738,688 (20,480)
//   inv_dv   f32  20480        @ 26,759,168 (81,920)
//   xpb      img  2560x256x16B @ 26,841,088 (10,485,760)
//   partialA f32  8x256x5120   @ 37,326,848 (41,943,040)
//   t2p      img  640x256x16B  @ 79,269,888 (2,621,440)
//   T3       bf16 20000x256    @ 81,891,328 (10,240,000)   total ~92 MB

#define N_NODES 20000
#define M_EDGES 5000
#define MPAD    5120
#define NPAD    20480
#define NW      320
#define MW      80
#define DIN     256
#define DOUT    512
#define SPLITS  8

typedef short bf16x8 __attribute__((ext_vector_type(8)));
typedef float f32x4 __attribute__((ext_vector_type(4)));
typedef unsigned long long u64;

#define MFMA16(A, B, C) __builtin_amdgcn_mfma_f32_16x16x32_bf16((A), (B), (C), 0, 0, 0)

__device__ __forceinline__ unsigned short f2b(float f) {
  unsigned u = __builtin_bit_cast(unsigned, f);
  return (unsigned short)((u + 0x7FFFu + ((u >> 16) & 1u)) >> 16);  // RNE
}

__device__ __forceinline__ void stage16(const void* g, void* l) {
  __builtin_amdgcn_global_load_lds(
      (const __attribute__((address_space(1))) unsigned int*)g,
      (__attribute__((address_space(3))) unsigned int*)l, 16, 0, 0);
}

// 8 bits -> 8 bf16 {0,1}: t = b|(b<<15); pair p = ((t>>2p)&0x00010001)*0x3F80
__device__ __forceinline__ bf16x8 expand8(unsigned b) {
  union { unsigned u[4]; bf16x8 v; } r;
  const unsigned t = b | (b << 15);
  r.u[0] = (t & 0x00010001u) * 0x3F80u;
  r.u[1] = ((t >> 2) & 0x00010001u) * 0x3F80u;
  r.u[2] = ((t >> 4) & 0x00010001u) * 0x3F80u;
  r.u[3] = ((t >> 6) & 0x00010001u) * 0x3F80u;
  return r.v;
}

// ---------------------------------------------------------------- prep
__global__ __launch_bounds__(256) void prep_kernel(const float* __restrict__ Wn,
                                                   const float* __restrict__ Wr,
                                                   unsigned short* __restrict__ WT) {
  const int q = blockIdx.x * 256 + threadIdx.x;  // < 262144
  const int j = q >> 9, k = q & 511;
  const float v = (k < 256) ? Wn[(size_t)k * 512 + j] : Wr[(size_t)(k - 256) * 512 + j];
  WT[(size_t)j * 512 + k] = f2b(v);
}

// ---------------------------------------------------------------- xt: x -> xpb frag image [n8][j] x 8 bf16
__global__ __launch_bounds__(256) void xt_kernel(const float* __restrict__ x,
                                                 unsigned short* __restrict__ xpb) {
  const int j = threadIdx.x;       // 0..255
  const int n8 = blockIdx.x;       // 0..2559
  union { unsigned u[4]; bf16x8 v; } o;
#pragma unroll
  for (int p = 0; p < 4; ++p) {
    const int n = n8 * 8 + 2 * p;
    const float v0 = (n < N_NODES) ? x[(size_t)n * DIN + j] : 0.f;
    const float v1 = (n + 1 < N_NODES) ? x[(size_t)(n + 1) * DIN + j] : 0.f;
    o.u[p] = (unsigned)f2b(v0) | ((unsigned)f2b(v1) << 16);
  }
  *(bf16x8*)(xpb + ((size_t)n8 * 256 + j) * 8) = o.v;
}

// ---------------------------------------------------------------- pack: H f32 -> bitmasks, both orientations
__global__ __launch_bounds__(256) void pack_kernel(const float* __restrict__ H,
                                                   u64* __restrict__ Hb,
                                                   u64* __restrict__ HTb) {
  const int t = threadIdx.x;
  const int w = t >> 6, l = t & 63;
  const int nb = blockIdx.x;   // 0..319
  const int mb = blockIdx.y;   // 0..19
  const int m = mb * 256 + w * 64 + l;
  const bool mv = m < M_EDGES;
  unsigned lo = 0, hi = 0;
  u64 myword = 0;
#pragma unroll 8
  for (int k = 0; k < 64; ++k) {
    const int n = nb * 64 + k;
    float v = 0.f;
    if (mv && n < N_NODES) v = H[(size_t)n * M_EDGES + m];
    const bool p = (v != 0.f);
    const u64 mask = __ballot(p);
    if (l == k) myword = mask;
    if (k < 32) lo |= (p ? 1u : 0u) << k;
    else        hi |= (p ? 1u : 0u) << (k - 32);
  }
  Hb[(size_t)(mb * 4 + w) * NPAD + nb * 64 + l] = myword;       // [mw][n]
  HTb[(size_t)nb * MPAD + m] = ((u64)hi << 32) | lo;            // [nw][m]
}

// ---------------------------------------------------------------- deg
__global__ __launch_bounds__(256) void deg_kernel(const u64* __restrict__ Hb,
                                                  const u64* __restrict__ HTb,
                                                  float* __restrict__ inv_de,
                                                  float* __restrict__ inv_dv) {
  const int g = blockIdx.x * 256 + threadIdx.x;
  if (g < MPAD) {
    int c = 0;
    for (int nw = 0; nw < NW; ++nw) c += __popcll(HTb[(size_t)nw * MPAD + g]);
    inv_de[g] = 1.f / fmaxf((float)c, 1.f);
  } else if (g < MPAD + NPAD) {
    const int n = g - MPAD;
    int c = 0;
#pragma unroll
    for (int mw = 0; mw < MW; ++mw) c += __popcll(Hb[(size_t)mw * NPAD + n]);
    inv_dv[n] = 1.f / fmaxf((float)c, 1.f);
  }
}

// ---------------------------------------------------------------- gemmA: partialA[s] = x^T @ H
// 4 waves, block tile 64j x 256m (wave-private 64m), K-split 8 (40 steps of 64n).
// A (xpb) -> LDS frag image via gload_lds; B (HTb bits) -> reg ping-pong.
// grid 640 1-D: mchunk = wgid>>5; sj = wgid&31 (s=sj>>2, j=sj&3) -> xcd = sj%8.
__global__ __launch_bounds__(256) void gemmA_kernel(const unsigned short* __restrict__ xpb,
                                                    const u64* __restrict__ HTb,
                                                    float* __restrict__ partial) {
  __shared__ char lds[2][8192];
  const int t = threadIdx.x;
  const int w = t >> 6, l = t & 63;
  const int lr = l & 15, lg = l >> 4;
  const int shl8 = lg * 8;
  const int wgid = blockIdx.x;
  const int mchunk = wgid >> 5;
  const int sj = wgid & 31;
  const int s = sj >> 2, jb = sj & 3;
  const int m0 = mchunk * 256 + w * 64;
  const int j0 = jb * 64;

  f32x4 acc[4][4] = {};
  const u64* bbase = HTb + (size_t)(s * 40) * MPAD + m0 + lr;
  const char* xb = (const char*)xpb;
  const int n8b = s * 320;
  const int sj0 = j0 + w * 16 + lr;   // staging column (fr = w)

  u64 b00, b01, b02, b03, b10, b11, b12, b13;

#define GA_LOADB(S, st_) do {                                                  \
    const u64* bp_ = bbase + (size_t)(st_) * MPAD;                             \
    b##S##0 = bp_[0]; b##S##1 = bp_[16]; b##S##2 = bp_[32]; b##S##3 = bp_[48]; \
  } while (0)

#define GA_STAGE(buf, st_) do {                                                \
    const size_t s0_ = ((size_t)(n8b + (st_) * 8 + lg) * 256 + sj0) * 16;      \
    const size_t s1_ = ((size_t)(n8b + (st_) * 8 + 4 + lg) * 256 + sj0) * 16;  \
    stage16(xb + s0_, &lds[buf][w * 1024 + l * 16]);                           \
    stage16(xb + s1_, &lds[buf][(4 + w) * 1024 + l * 16]);                     \
  } while (0)

#define GA_JG(jg, BW) do {                                                     \
    const unsigned wlo_ = (unsigned)(BW), whi_ = (unsigned)((BW) >> 32);       \
    const bf16x8 e0_ = expand8((wlo_ >> shl8) & 255u);                         \
    const bf16x8 e1_ = expand8((whi_ >> shl8) & 255u);                         \
    acc[0][jg] = MFMA16(A00_, e0_, acc[0][jg]);                                \
    acc[1][jg] = MFMA16(A10_, e0_, acc[1][jg]);                                \
    acc[2][jg] = MFMA16(A20_, e0_, acc[2][jg]);                                \
    acc[3][jg] = MFMA16(A30_, e0_, acc[3][jg]);                                \
    acc[0][jg] = MFMA16(A01_, e1_, acc[0][jg]);                                \
    acc[1][jg] = MFMA16(A11_, e1_, acc[1][jg]);                                \
    acc[2][jg] = MFMA16(A21_, e1_, acc[2][jg]);                                \
    acc[3][jg] = MFMA16(A31_, e1_, acc[3][jg]);                                \
  } while (0)

#define GA_COMP(buf, S) do {                                                   \
    const char* L_ = &lds[buf][0];                                             \
    const bf16x8 A00_ = *(const bf16x8*)(L_ + l * 16 + 0);                     \
    const bf16x8 A10_ = *(const bf16x8*)(L_ + l * 16 + 1024);                  \
    const bf16x8 A20_ = *(const bf16x8*)(L_ + l * 16 + 2048);                  \
    const bf16x8 A30_ = *(const bf16x8*)(L_ + l * 16 + 3072);                  \
    const bf16x8 A01_ = *(const bf16x8*)(L_ + l * 16 + 4096);                  \
    const bf16x8 A11_ = *(const bf16x8*)(L_ + l * 16 + 5120);                  \
    const bf16x8 A21_ = *(const bf16x8*)(L_ + l * 16 + 6144);                  \
    const bf16x8 A31_ = *(const bf16x8*)(L_ + l * 16 + 7168);                  \
    GA_JG(0, b##S##0); GA_JG(1, b##S##1); GA_JG(2, b##S##2); GA_JG(3, b##S##3);\
  } while (0)

  GA_LOADB(0, 0);
  GA_STAGE(0, 0);
  for (int st = 0; st < 40; st += 2) {
    const int n1 = (st + 1 < 40) ? st + 1 : 39;
    GA_LOADB(1, n1); GA_STAGE(1, n1);
    asm volatile("s_waitcnt vmcnt(6)" ::: "memory");
    __builtin_amdgcn_s_barrier();
    GA_COMP(0, 0);
    __builtin_amdgcn_s_barrier();
    const int n2 = (st + 2 < 40) ? st + 2 : 39;
    GA_LOADB(0, n2); GA_STAGE(0, n2);
    asm volatile("s_waitcnt vmcnt(6)" ::: "memory");
    __builtin_amdgcn_s_barrier();
    GA_COMP(1, 1);
    __builtin_amdgcn_s_barrier();
  }
#undef GA_LOADB
#undef GA_STAGE
#undef GA_JG
#undef GA_COMP

  float* pp = partial + (size_t)s * (DIN * MPAD);
#pragma unroll
  for (int fr = 0; fr < 4; ++fr)
#pragma unroll
    for (int r = 0; r < 4; ++r) {
      const int j = j0 + fr * 16 + lg * 4 + r;
#pragma unroll
      for (int jg = 0; jg < 4; ++jg)
        pp[(size_t)j * MPAD + m0 + jg * 16 + lr] = acc[fr][jg][r];
    }
}

// ---------------------------------------------------------------- reduceA: coalesced (m on threads)
__global__ __launch_bounds__(256) void reduceA_kernel(const float* __restrict__ partial,
                                                      const float* __restrict__ inv_de,
                                                      unsigned short* __restrict__ t2p) {
  const int t = threadIdx.x;
  const int m = blockIdx.x * 256 + t;       // 0..5119
  const int jc = blockIdx.y * 16;           // 16 j per block
  const float e = inv_de[m];
  unsigned short* ob = t2p + ((size_t)(m >> 3) * 256) * 8 + (m & 7);
  for (int jj = 0; jj < 16; ++jj) {
    const int j = jc + jj;
    const float* p = partial + (size_t)j * MPAD + m;
    float s = 0.f;
#pragma unroll
    for (int sp = 0; sp < SPLITS; ++sp) s += p[(size_t)sp * (DIN * MPAD)];
    ob[(size_t)j * 8] = f2b(s * e);
  }
}

// ---------------------------------------------------------------- gemmB: T3 = bf16((H @ T2)/d_v)
// 4 waves, block tile 256n (wave-private 64) x 64j, 80 steps of 64m.
// B (t2p) -> LDS frag image via gload_lds; A (Hb bits) -> reg ping-pong.
// grid 316 1-D: nchunk = wgid>>2, jb = wgid&3.
__global__ __launch_bounds__(256) void gemmB_kernel(const unsigned short* __restrict__ t2p,
                                                    const u64* __restrict__ Hb,
                                                    const float* __restrict__ inv_dv,
                                                    unsigned short* __restrict__ T3) {
  __shared__ char lds[2][8192];
  const int t = threadIdx.x;
  const int w = t >> 6, l = t & 63;
  const int lr = l & 15, lg = l >> 4;
  const int shl8 = lg * 8;
  const int wgid = blockIdx.x;
  const int nchunk = wgid >> 2;
  const int jb = wgid & 3;
  const int n0 = nchunk * 256 + w * 64;
  const int j0 = jb * 64;

  f32x4 acc[4][4] = {};
  const u64* abase = Hb + n0 + lr;
  const char* tb = (const char*)t2p;
  const int sj0 = j0 + w * 16 + lr;   // staging column (jg = w)

  u64 a00, a01, a02, a03, a10, a11, a12, a13;

#define GB_LOADA(S, st_) do {                                                  \
    const u64* ap_ = abase + (size_t)(st_) * NPAD;                             \
    a##S##0 = ap_[0]; a##S##1 = ap_[16]; a##S##2 = ap_[32]; a##S##3 = ap_[48]; \
  } while (0)

#define GB_STAGE(buf, st_) do {                                                \
    const size_t s0_ = ((size_t)((st_) * 8 + lg) * 256 + sj0) * 16;            \
    const size_t s1_ = ((size_t)((st_) * 8 + 4 + lg) * 256 + sj0) * 16;        \
    stage16(tb + s0_, &lds[buf][w * 1024 + l * 16]);                           \
    stage16(tb + s1_, &lds[buf][(4 + w) * 1024 + l * 16]);                     \
  } while (0)

#define GB_FR(fr, AW) do {                                                     \
    const unsigned wlo_ = (unsigned)(AW), whi_ = (unsigned)((AW) >> 32);       \
    const bf16x8 e0_ = expand8((wlo_ >> shl8) & 255u);                         \
    const bf16x8 e1_ = expand8((whi_ >> shl8) & 255u);                         \
    acc[fr][0] = MFMA16(e0_, B00_, acc[fr][0]);                                \
    acc[fr][1] = MFMA16(e0_, B10_, acc[fr][1]);                                \
    acc[fr][2] = MFMA16(e0_, B20_, acc[fr][2]);                                \
    acc[fr][3] = MFMA16(e0_, B30_, acc[fr][3]);                                \
    acc[fr][0] = MFMA16(e1_, B01_, acc[fr][0]);                                \
    acc[fr][1] = MFMA16(e1_, B11_, acc[fr][1]);                                \
    acc[fr][2] = MFMA16(e1_, B21_, acc[fr][2]);                                \
    acc[fr][3] = MFMA16(e1_, B31_, acc[fr][3]);                                \
  } while (0)

#define GB_COMP(buf, S) do {                                                   \
    const char* L_ = &lds[buf][0];                                             \
    const bf16x8 B00_ = *(const bf16x8*)(L_ + l * 16 + 0);                     \
    const bf16x8 B10_ = *(const bf16x8*)(L_ + l * 16 + 1024);                  \
    const bf16x8 B20_ = *(const bf16x8*)(L_ + l * 16 + 2048);                  \
    const bf16x8 B30_ = *(const bf16x8*)(L_ + l * 16 + 3072);                  \
    const bf16x8 B01_ = *(const bf16x8*)(L_ + l * 16 + 4096);                  \
    const bf16x8 B11_ = *(const bf16x8*)(L_ + l * 16 + 5120);                  \
    const bf16x8 B21_ = *(const bf16x8*)(L_ + l * 16 + 6144);                  \
    const bf16x8 B31_ = *(const bf16x8*)(L_ + l * 16 + 7168);                  \
    GB_FR(0, a##S##0); GB_FR(1, a##S##1); GB_FR(2, a##S##2); GB_FR(3, a##S##3);\
  } while (0)

  GB_LOADA(0, 0);
  GB_STAGE(0, 0);
  for (int st = 0; st < 80; st += 2) {
    const int n1 = (st + 1 < 80) ? st + 1 : 79;
    GB_LOADA(1, n1); GB_STAGE(1, n1);
    asm volatile("s_waitcnt vmcnt(6)" ::: "memory");
    __builtin_amdgcn_s_barrier();
    GB_COMP(0, 0);
    __builtin_amdgcn_s_barrier();
    const int n2 = (st + 2 < 80) ? st + 2 : 79;
    GB_LOADA(0, n2); GB_STAGE(0, n2);
    asm volatile("s_waitcnt vmcnt(6)" ::: "memory");
    __builtin_amdgcn_s_barrier();
    GB_COMP(1, 1);
    __builtin_amdgcn_s_barrier();
  }
#undef GB_LOADA
#undef GB_STAGE
#undef GB_FR
#undef GB_COMP

#pragma unroll
  for (int fr = 0; fr < 4; ++fr) {
    const f32x4 dv = *(const f32x4*)(inv_dv + n0 + fr * 16 + lg * 4);
#pragma unroll
    for (int r = 0; r < 4; ++r) {
      const int n = n0 + fr * 16 + lg * 4 + r;
      if (n < N_NODES) {
#pragma unroll
        for (int jg = 0; jg < 4; ++jg)
          T3[(size_t)n * DIN + j0 + jg * 16 + lr] = f2b(acc[fr][jg][r] * dv[r]);
      }
    }
  }
}

// ---------------------------------------------------------------- gemmC: out = [T3 | x] @ WT_cat (f32)
__global__ __launch_bounds__(512) void gemmC_kernel(const float* __restrict__ x,
                                                    const unsigned short* __restrict__ T3,
                                                    const unsigned short* __restrict__ WT,
                                                    float* __restrict__ out) {
  __shared__ unsigned short As[128 * 64];
  __shared__ unsigned short Bsh[128 * 64];
  const int t = threadIdx.x;
  const int n0 = blockIdx.x * 128;
  const int j0 = blockIdx.y * 128;
  const int w = t >> 6, l = t & 63;
  const int wr = w >> 2, wc = w & 3;
  const int lr = l & 15, lg = l >> 4;
  f32x4 acc[4][2];
#pragma unroll
  for (int i = 0; i < 4; ++i)
#pragma unroll
    for (int jq = 0; jq < 2; ++jq) acc[i][jq] = (f32x4){0.f, 0.f, 0.f, 0.f};
  const int sr = t >> 3, sk8 = t & 7;

  for (int st = 0; st < 8; ++st) {
    __syncthreads();
#pragma unroll
    for (int p = 0; p < 2; ++p) {
      const int node = sr + p * 64;
      const int gn = n0 + node;
      bf16x8 pk;
      if (st < 4) {
        if (gn < N_NODES)
          pk = *(const bf16x8*)(T3 + (size_t)gn * DIN + st * 64 + sk8 * 8);
        else {
#pragma unroll
          for (int jq = 0; jq < 8; ++jq) pk[jq] = 0;
        }
      } else {
        if (gn < N_NODES) {
          const float4* p4 = (const float4*)(x + (size_t)gn * DIN + (st - 4) * 64 + sk8 * 8);
          const float4 q0 = p4[0], q1 = p4[1];
          pk[0] = (short)f2b(q0.x); pk[1] = (short)f2b(q0.y); pk[2] = (short)f2b(q0.z); pk[3] = (short)f2b(q0.w);
          pk[4] = (short)f2b(q1.x); pk[5] = (short)f2b(q1.y); pk[6] = (short)f2b(q1.z); pk[7] = (short)f2b(q1.w);
        } else {
#pragma unroll
          for (int jq = 0; jq < 8; ++jq) pk[jq] = 0;
        }
      }
      *(bf16x8*)((char*)As + node * 128 + ((sk8 * 16) ^ ((node & 7) << 4))) = pk;
    }
#pragma unroll
    for (int p = 0; p < 2; ++p) {
      const int j = sr + p * 64;
      const bf16x8 pk = *(const bf16x8*)(WT + (size_t)(j0 + j) * 512 + st * 64 + sk8 * 8);
      *(bf16x8*)((char*)Bsh + j * 128 + ((sk8 * 16) ^ ((j & 7) << 4))) = pk;
    }
    __syncthreads();
#pragma unroll
    for (int ks = 0; ks < 2; ++ks) {
      const int kb = ks * 64 + 16 * lg;
      bf16x8 bf[2];
#pragma unroll
      for (int fc = 0; fc < 2; ++fc) {
        const int row = wc * 32 + fc * 16 + lr;
        bf[fc] = *(const bf16x8*)((const char*)Bsh + row * 128 + (kb ^ ((row & 7) << 4)));
      }
#pragma unroll
      for (int fr = 0; fr < 4; ++fr) {
        const int row = wr * 64 + fr * 16 + lr;
        const bf16x8 af = *(const bf16x8*)((const char*)As + row * 128 + (kb ^ ((row & 7) << 4)));
#pragma unroll
        for (int fc = 0; fc < 2; ++fc)
          acc[fr][fc] = __builtin_amdgcn_mfma_f32_16x16x32_bf16(af, bf[fc], acc[fr][fc], 0, 0, 0);
      }
    }
  }
#pragma unroll
  for (int fr = 0; fr < 4; ++fr)
#pragma unroll
    for (int fc = 0; fc < 2; ++fc) {
      const int col = j0 + wc * 32 + fc * 16 + lr;
#pragma unroll
      for (int r = 0; r < 4; ++r) {
        const int row = n0 + wr * 64 + fr * 16 + 4 * lg + r;
        if (row < N_NODES) out[(size_t)row * DOUT + col] = acc[fr][fc][r];
      }
    }
}

// ---------------------------------------------------------------- LayerNorm (in place on out)
__global__ __launch_bounds__(256) void ln_kernel(float* __restrict__ out,
                                                 const float* __restrict__ gamma,
                                                 const float* __restrict__ beta) {
  const int row = blockIdx.x * 4 + (threadIdx.x >> 6);
  const int l = threadIdx.x & 63;
  float* p = out + (size_t)row * DOUT;
  float4 va = *(const float4*)(p + 4 * l);
  float4 vb = *(const float4*)(p + 256 + 4 * l);
  float s = va.x + va.y + va.z + va.w + vb.x + vb.y + vb.z + vb.w;
  float s2 = va.x * va.x + va.y * va.y + va.z * va.z + va.w * va.w +
             vb.x * vb.x + vb.y * vb.y + vb.z * vb.z + vb.w * vb.w;
#pragma unroll
  for (int m = 1; m < 64; m <<= 1) { s += __shfl_xor(s, m, 64); s2 += __shfl_xor(s2, m, 64); }
  const float mu = s * (1.f / DOUT);
  const float rs = rsqrtf(s2 * (1.f / DOUT) - mu * mu + 1e-5f);
  const float4 g0 = *(const float4*)(gamma + 4 * l);
  const float4 g1 = *(const float4*)(gamma + 256 + 4 * l);
  const float4 b0 = *(const float4*)(beta + 4 * l);
  const float4 b1 = *(const float4*)(beta + 256 + 4 * l);
  va.x = (va.x - mu) * rs * g0.x + b0.x;  va.y = (va.y - mu) * rs * g0.y + b0.y;
  va.z = (va.z - mu) * rs * g0.z + b0.z;  va.w = (va.w - mu) * rs * g0.w + b0.w;
  vb.x = (vb.x - mu) * rs * g1.x + b1.x;  vb.y = (vb.y - mu) * rs * g1.y + b1.y;
  vb.z = (vb.z - mu) * rs * g1.z + b1.z;  vb.w = (vb.w - mu) * rs * g1.w + b1.w;
  *(float4*)(p + 4 * l) = va;
  *(float4*)(p + 256 + 4 * l) = vb;
}

// ----------------------------------------------------------------
extern "C" void kernel_launch(void* const* d_in, const int* in_sizes, int n_in,
                              void* d_out, int out_size, void* d_ws, size_t ws_size,
                              hipStream_t stream) {
  (void)in_sizes; (void)n_in; (void)out_size; (void)ws_size;
  const float* x = (const float*)d_in[0];
  const float* H = (const float*)d_in[1];
  const float* Wn = (const float*)d_in[2];
  const float* Wr = (const float*)d_in[3];
  const float* gamma = (const float*)d_in[4];
  const float* beta = (const float*)d_in[5];
  float* out = (float*)d_out;
  char* ws = (char*)d_ws;

  unsigned short* WT  = (unsigned short*)(ws + 0);
  u64* Hb             = (u64*)(ws + 524288);
  u64* HTb            = (u64*)(ws + 13631488);
  float* inv_de       = (float*)(ws + 26738688);
  float* inv_dv       = (float*)(ws + 26759168);
  unsigned short* xpb = (unsigned short*)(ws + 26841088);
  float* partial      = (float*)(ws + 37326848);
  unsigned short* t2p = (unsigned short*)(ws + 79269888);
  unsigned short* T3  = (unsigned short*)(ws + 81891328);

  prep_kernel<<<dim3(1024), dim3(256), 0, stream>>>(Wn, Wr, WT);
  xt_kernel<<<dim3(2560), dim3(256), 0, stream>>>(x, xpb);
  pack_kernel<<<dim3(320, 20), dim3(256), 0, stream>>>(H, Hb, HTb);
  deg_kernel<<<dim3(100), dim3(256), 0, stream>>>(Hb, HTb, inv_de, inv_dv);
  gemmA_kernel<<<dim3(640), dim3(256), 0, stream>>>(xpb, HTb, partial);
  reduceA_kernel<<<dim3(20, 16), dim3(256), 0, stream>>>(partial, inv_de, t2p);
  gemmB_kernel<<<dim3(316), dim3(256), 0, stream>>>(t2p, Hb, inv_dv, T3);
  gemmC_kernel<<<dim3(157, 4), dim3(512), 0, stream>>>(x, T3, WT, out);
  ln_kernel<<<dim3(5000), dim3(256), 0, stream>>>(out, gamma, beta);
}